// Round 4
// baseline (975.144 us; speedup 1.0000x reference)
//
#include <hip/hip_runtime.h>
#include <stdint.h>

typedef __bf16 bf16_t;
typedef bf16_t bf16x8 __attribute__((ext_vector_type(8)));
typedef float f32x4 __attribute__((ext_vector_type(4)));

typedef unsigned int u32;
typedef __attribute__((address_space(1))) const u32 gu32;
typedef __attribute__((address_space(3))) u32 lu32;

#define LN_EPS 1e-5f
#define EPS_ 1e-8f
#define SCALE_ 0.04419417382415922f  // 512^-0.5

__device__ __forceinline__ float wave_red_sum(float v) {
#pragma unroll
  for (int off = 32; off > 0; off >>= 1) v += __shfl_xor(v, off, 64);
  return v;
}

// ---------------- prep: LDS-tiled transposes (coalesced both sides) ----------------
__global__ __launch_bounds__(256) void transpose_prep(
    const float* __restrict__ Wk, const float* __restrict__ Wv,
    const float* __restrict__ wih, const float* __restrict__ whh,
    bf16_t* __restrict__ BT, float* __restrict__ wihT, float* __restrict__ whhT)
{
  int z = blockIdx.z;
  if (z < 2 && blockIdx.y >= 16) return;
  const float* src = (z == 0) ? Wk : (z == 1) ? Wv : (z == 2) ? wih : whh;
  __shared__ float tile[32][33];
  int tx = threadIdx.x & 31, ty = threadIdx.x >> 5;  // 32 x 8
  int row0 = blockIdx.y * 32, col0 = blockIdx.x * 32;
#pragma unroll
  for (int i = 0; i < 4; ++i)
    tile[ty + 8 * i][tx] = src[(size_t)(row0 + ty + 8 * i) * 512 + col0 + tx];
  __syncthreads();
  if (z < 2) {
#pragma unroll
    for (int i = 0; i < 4; ++i)
      BT[(size_t)(z * 512 + col0 + ty + 8 * i) * 512 + row0 + tx] =
          (bf16_t)tile[tx][ty + 8 * i];
  } else {
    float* dst = (z == 2) ? wihT : whhT;
#pragma unroll
    for (int i = 0; i < 4; ++i)
      dst[(size_t)(col0 + ty + 8 * i) * 1536 + row0 + tx] = tile[tx][ty + 8 * i];
  }
}

// ---------------- small prep: biasc pack + slots init (into d_out) ----------------
__global__ __launch_bounds__(256) void small_prep(
    const float* __restrict__ bk, const float* __restrict__ bv,
    const float* __restrict__ slots_init,
    float* __restrict__ biasc, float* __restrict__ slots)
{
  int idx = blockIdx.x * 256 + threadIdx.x;  // < 33792
  if (idx < 1024) {
    biasc[idx] = (idx < 512) ? bk[idx] : bv[idx - 512];
  } else {
    int i = idx - 1024;  // < 32768
    slots[i] = slots_init[i];
  }
}

// ---------------- LN(inputs) -> bf16, one wave per row ----------------
__global__ __launch_bounds__(256) void ln_apply(
    const float* __restrict__ in, const float* __restrict__ lng,
    const float* __restrict__ lnb, bf16_t* __restrict__ xbf)
{
  int w = threadIdx.x >> 6, lane = threadIdx.x & 63;
  size_t row = (size_t)blockIdx.x * 4 + w;
  const float4* rp = (const float4*)(in + row * 512);
  float4 a = rp[lane * 2], c = rp[lane * 2 + 1];
  float s1 = a.x + a.y + a.z + a.w + c.x + c.y + c.z + c.w;
  float s2 = a.x * a.x + a.y * a.y + a.z * a.z + a.w * a.w +
             c.x * c.x + c.y * c.y + c.z * c.z + c.w * c.w;
  s1 = wave_red_sum(s1);
  s2 = wave_red_sum(s2);
  float mean = s1 * (1.f / 512.f);
  float var = s2 * (1.f / 512.f) - mean * mean;
  float rs = rsqrtf(var + LN_EPS);
  float4 g0 = *(const float4*)&lng[lane * 8];
  float4 g1 = *(const float4*)&lng[lane * 8 + 4];
  float4 b0 = *(const float4*)&lnb[lane * 8];
  float4 b1 = *(const float4*)&lnb[lane * 8 + 4];
  bf16x8 o;
  o[0] = (bf16_t)((a.x - mean) * rs * g0.x + b0.x);
  o[1] = (bf16_t)((a.y - mean) * rs * g0.y + b0.y);
  o[2] = (bf16_t)((a.z - mean) * rs * g0.z + b0.z);
  o[3] = (bf16_t)((a.w - mean) * rs * g0.w + b0.w);
  o[4] = (bf16_t)((c.x - mean) * rs * g1.x + b1.x);
  o[5] = (bf16_t)((c.y - mean) * rs * g1.y + b1.y);
  o[6] = (bf16_t)((c.z - mean) * rs * g1.z + b1.z);
  o[7] = (bf16_t)((c.w - mean) * rs * g1.w + b1.w);
  *(bf16x8*)&xbf[row * 512 + lane * 8] = o;
}

// ---------------- pure bf16 MFMA GEMM, XCD-swizzled, swizzled LDS ----------------
__global__ __launch_bounds__(256) void gemm_kv(
    const bf16_t* __restrict__ xbf, const bf16_t* __restrict__ BT,
    const float* __restrict__ biasc,
    float* __restrict__ out_k, bf16_t* __restrict__ vbf)
{
  __shared__ __align__(16) char smem[16384];
  bf16_t* As = (bf16_t*)smem;             // 128 x 32 bf16 (swizzled granules)
  bf16_t* Bs = (bf16_t*)(smem + 8192);    // 128 x 32 bf16 (swizzled granules)
  float (*Cs)[132] = (float(*)[132])smem; // 16 x 132 fp32 (epilogue reuse)

  const int tid = threadIdx.x, lane = tid & 63, w = tid >> 6;
  const int quad = lane >> 4, l16 = lane & 15;
  const int l = blockIdx.x;
  const int x = l & 7, t = l >> 3;
  const int n0 = (t & 7) * 128;
  const int m0 = ((t >> 3) * 8 + x) * 128;
  const int mb = (w & 1) * 64, nb = (w >> 1) * 64;
  const int swz = (l16 >> 1) & 3;

  const bf16_t* a_base = xbf + (size_t)m0 * 512;
  const bf16_t* b_base = BT + (size_t)n0 * 512;

  f32x4 acc[4][4] = {};

  for (int kk = 0; kk < 512; kk += 32) {
#pragma unroll
    for (int r = 0; r < 2; ++r) {
      int tt = tid + r * 256;
      int rr = tt >> 2, pg = tt & 3;
      int lg = pg ^ ((rr >> 1) & 3);  // pre-swizzled source granule
      __builtin_amdgcn_global_load_lds((gu32*)(a_base + (size_t)rr * 512 + kk + lg * 8),
                                       (lu32*)&As[tt * 8], 16, 0, 0);
      __builtin_amdgcn_global_load_lds((gu32*)(b_base + (size_t)rr * 512 + kk + lg * 8),
                                       (lu32*)&Bs[tt * 8], 16, 0, 0);
    }
    __syncthreads();
    bf16x8 af[4], bfr[4];
#pragma unroll
    for (int mt = 0; mt < 4; ++mt)
      af[mt] = *(const bf16x8*)&As[(mb + mt * 16 + l16) * 32 + (quad ^ swz) * 8];
#pragma unroll
    for (int nt = 0; nt < 4; ++nt)
      bfr[nt] = *(const bf16x8*)&Bs[(nb + nt * 16 + l16) * 32 + (quad ^ swz) * 8];
#pragma unroll
    for (int mt = 0; mt < 4; ++mt)
#pragma unroll
      for (int nt = 0; nt < 4; ++nt)
        acc[mt][nt] = __builtin_amdgcn_mfma_f32_16x16x32_bf16(af[mt], bfr[nt], acc[mt][nt], 0, 0, 0);
    __syncthreads();
  }

  const int is_k = (n0 < 512);
  const int col4 = (tid * 4) & 127;
  const int row8 = tid >> 4;
  const int col8 = (tid * 8) & 127;
  for (int ci = 0; ci < 8; ++ci) {
    if ((ci < 4) == (mb == 0)) {
      int mt = ci & 3;
#pragma unroll
      for (int nt = 0; nt < 4; ++nt)
#pragma unroll
        for (int r = 0; r < 4; ++r)
          Cs[quad * 4 + r][nb + nt * 16 + l16] = acc[mt][nt][r];
    }
    __syncthreads();
    int rowbase = m0 + ci * 16;
    if (is_k) {
      f32x4 bias4 = *(const f32x4*)&biasc[n0 + col4];
#pragma unroll
      for (int p = 0; p < 2; ++p) {
        int f = p * 1024 + tid * 4;
        int row = f >> 7;
        f32x4 v = *(const f32x4*)&Cs[row][col4] + bias4;
        *(f32x4*)&out_k[(size_t)(rowbase + row) * 512 + n0 + col4] = v;
      }
    } else {
      f32x4 ba = *(const f32x4*)&biasc[n0 + col8];
      f32x4 bb = *(const f32x4*)&biasc[n0 + col8 + 4];
      f32x4 v0 = *(const f32x4*)&Cs[row8][col8] + ba;
      f32x4 v1 = *(const f32x4*)&Cs[row8][col8 + 4] + bb;
      bf16x8 o;
#pragma unroll
      for (int j = 0; j < 4; ++j) { o[j] = (bf16_t)v0[j]; o[4 + j] = (bf16_t)v1[j]; }
      *(bf16x8*)&vbf[(size_t)(rowbase + row8) * 512 + (n0 - 512) + col8] = o;
    }
    __syncthreads();
  }
}

// ---------------- ln_q: LN(slots) + q GEMV, once per iteration ----------------
// grid 32: block b computes q rows 2b, 2b+1 into q_out
__global__ __launch_bounds__(256) void ln_q_kernel(
    const float* __restrict__ slots,
    const float* __restrict__ lnsg, const float* __restrict__ lnsb,
    const float* __restrict__ Wq, const float* __restrict__ bq,
    float* __restrict__ q_out)
{
  __shared__ float s[2][512];
  __shared__ float red1[4], red2[4];
  int tid = threadIdx.x, w = tid >> 6, lane = tid & 63;
  int b = blockIdx.x;

  int r = tid >> 7;
  int off = (tid * 4) & 511;
  float4 v = *(const float4*)&slots[b * 1024 + tid * 4];
  float s1 = v.x + v.y + v.z + v.w;
  float s2 = v.x * v.x + v.y * v.y + v.z * v.z + v.w * v.w;
  s1 = wave_red_sum(s1);
  s2 = wave_red_sum(s2);
  if (lane == 0) { red1[w] = s1; red2[w] = s2; }
  __syncthreads();
  float mean = (red1[r * 2] + red1[r * 2 + 1]) * (1.f / 512.f);
  float var = (red2[r * 2] + red2[r * 2 + 1]) * (1.f / 512.f) - mean * mean;
  float rstd = rsqrtf(var + LN_EPS);
  float4 g4 = *(const float4*)&lnsg[off];
  float4 b4 = *(const float4*)&lnsb[off];
  s[r][off + 0] = (v.x - mean) * rstd * g4.x + b4.x;
  s[r][off + 1] = (v.y - mean) * rstd * g4.y + b4.y;
  s[r][off + 2] = (v.z - mean) * rstd * g4.z + b4.z;
  s[r][off + 3] = (v.w - mean) * rstd * g4.w + b4.w;
  __syncthreads();

  int c = tid * 2;
  float a0 = 0.f, a1 = 0.f, a2 = 0.f, a3 = 0.f;
  for (int d = 0; d < 512; ++d) {
    float2 wv = *(const float2*)&Wq[d * 512 + c];
    float s0d = s[0][d], s1d = s[1][d];
    a0 += s0d * wv.x; a1 += s0d * wv.y;
    a2 += s1d * wv.x; a3 += s1d * wv.y;
  }
  float2 bq2 = *(const float2*)&bq[c];
  q_out[(b * 2 + 0) * 512 + c]     = a0 + bq2.x;
  q_out[(b * 2 + 0) * 512 + c + 1] = a1 + bq2.y;
  q_out[(b * 2 + 1) * 512 + c]     = a2 + bq2.x;
  q_out[(b * 2 + 1) * 512 + c + 1] = a3 + bq2.y;
}

// ---------------- attend v2: per-lane-j dots (no shuffle chains), LDS p handoff ----------------
// grid 1024 = 32 b x 32 chunks of 64 j; upd/rowsum pre-zeroed by memset.
// Phase 1: wave w owns j's [w*16, w*16+16); lane = (j within 16) + 16*(d-quarter).
// Phase 2: wave w owns same 16 j's; lanes span d (8 each); p broadcast from LDS.
__global__ __launch_bounds__(256) void attend_fused(
    const float* __restrict__ kf, const bf16_t* __restrict__ vbf,
    const float* __restrict__ qf,
    float* __restrict__ upd, float* __restrict__ rowsum,
    float* __restrict__ attn_pre)
{
  __shared__ float qs[2][528];   // [slot][dq*132 + dd] -- 132 pitch: quad bases hit banks 0,4,8,12
  __shared__ float p_s[2][64];
  int tid = threadIdx.x, w = tid >> 6, lane = tid & 63;
  int b = blockIdx.x >> 5, chunk = blockIdx.x & 31;
  int j0 = chunk * 64;

  // stage q[2][512] into LDS (pitched)
  {
    int slot = tid >> 7, pos = (tid & 127) * 4;
    int dq = pos >> 7, dd = pos & 127;
    *(f32x4*)&qs[slot][dq * 132 + dd] = *(const f32x4*)&qf[b * 1024 + slot * 512 + pos];
  }
  __syncthreads();

  // ---- phase 1: dots + softmax over slots, per-lane ----
  int jj = lane & 15;           // j within wave's 16
  int dq = lane >> 4;           // d quarter
  const float* kp = kf + (size_t)(b * 2048 + j0 + w * 16 + jj) * 512 + dq * 128;
  const float* qb0 = &qs[0][dq * 132];
  const float* qb1 = &qs[1][dq * 132];
  f32x4 acc0 = {0.f, 0.f, 0.f, 0.f};
  f32x4 acc1 = {0.f, 0.f, 0.f, 0.f};
  for (int d = 0; d < 128; d += 8) {
    f32x4 k0 = *(const f32x4*)(kp + d);
    f32x4 k1 = *(const f32x4*)(kp + d + 4);
    f32x4 qa0 = *(const f32x4*)(qb0 + d);
    f32x4 qa1 = *(const f32x4*)(qb0 + d + 4);
    f32x4 qc0 = *(const f32x4*)(qb1 + d);
    f32x4 qc1 = *(const f32x4*)(qb1 + d + 4);
    acc0 += k0 * qa0 + k1 * qa1;
    acc1 += k0 * qc0 + k1 * qc1;
  }
  float dot0 = acc0[0] + acc0[1] + acc0[2] + acc0[3];
  float dot1 = acc1[0] + acc1[1] + acc1[2] + acc1[3];
  // combine the 4 d-quarters (lanes differing in bits 4,5)
  dot0 += __shfl_xor(dot0, 16, 64);
  dot0 += __shfl_xor(dot0, 32, 64);
  dot1 += __shfl_xor(dot1, 16, 64);
  dot1 += __shfl_xor(dot1, 32, 64);
  float d0f = dot0 * SCALE_, d1f = dot1 * SCALE_;
  float mx = fmaxf(d0f, d1f);
  float e0 = __expf(d0f - mx), e1 = __expf(d1f - mx);
  float inv = 1.f / (e0 + e1);
  float p0 = e0 * inv, p1 = e1 * inv;
  if (lane < 16) {
    int jj2 = w * 16 + lane;
    p_s[0][jj2] = p0;
    p_s[1][jj2] = p1;
    attn_pre[(b * 2 + 0) * 2048 + j0 + jj2] = p0;
    attn_pre[(b * 2 + 1) * 2048 + j0 + jj2] = p1;
  }
  __syncthreads();

  // rowsum partials: wave 0 reduces the block's 64 p's per slot
  if (w == 0) {
    float a = p_s[0][lane];
    float c = p_s[1][lane];
    a = wave_red_sum(a);
    c = wave_red_sum(c);
    if (lane == 0) {
      atomicAdd(&rowsum[b * 2 + 0], a);
      atomicAdd(&rowsum[b * 2 + 1], c);
    }
  }

  // ---- phase 2: weighted-v accumulate, lanes over d ----
  float u0[8] = {}, u1[8] = {};
  const bf16_t* vp = vbf + (size_t)(b * 2048 + j0 + w * 16) * 512 + lane * 8;
  for (int t = 0; t < 16; ++t) {
    float p0b = p_s[0][w * 16 + t];
    float p1b = p_s[1][w * 16 + t];
    bf16x8 vv = *(const bf16x8*)(vp + (size_t)t * 512);
#pragma unroll
    for (int tt = 0; tt < 8; ++tt) {
      float vfl = (float)vv[tt];
      u0[tt] += p0b * vfl;
      u1[tt] += p1b * vfl;
    }
  }
#pragma unroll
  for (int tt = 0; tt < 8; ++tt) {
    atomicAdd(&upd[(b * 2 + 0) * 512 + lane * 8 + tt], u0[tt]);
    atomicAdd(&upd[(b * 2 + 1) * 512 + lane * 8 + tt], u1[tt]);
  }
}

// ---------------- gates: gx = u@wihT + bih, gh = h@whhT + bhh ----------------
__global__ __launch_bounds__(256) void gates_kernel(
    const float* __restrict__ slots, const float* __restrict__ upd,
    const float* __restrict__ rowsum,
    const float* __restrict__ wihT, const float* __restrict__ whhT,
    const float* __restrict__ bih, const float* __restrict__ bhh,
    float* __restrict__ gx, float* __restrict__ gh)
{
  __shared__ float in_s[2][512];
  __shared__ float part[4][2][256];
  int tid = threadIdx.x, w = tid >> 6, lane = tid & 63;
  int rg = blockIdx.x / 12, cc = blockIdx.x % 12;
  int is_gh = (cc >= 6);
  int ccl = is_gh ? cc - 6 : cc;
  {
    int rr = tid >> 7, pos = (tid & 127) * 4;
    int row = rg * 2 + rr;
    const float* src = (is_gh ? slots : upd) + row * 512;
    f32x4 v = *(const f32x4*)&src[pos];
    if (!is_gh) v *= 1.f / (rowsum[row] + EPS_);
    *(f32x4*)&in_s[rr][pos] = v;
  }
  __syncthreads();
  int c0 = ccl * 256 + lane * 4;
  const float* __restrict__ W = is_gh ? whhT : wihT;
  f32x4 acc0 = {0.f, 0.f, 0.f, 0.f}, acc1 = acc0;
  for (int d = w * 128; d < w * 128 + 128; ++d) {
    f32x4 w4 = *(const f32x4*)&W[d * 1536 + c0];
    acc0 += in_s[0][d] * w4;
    acc1 += in_s[1][d] * w4;
  }
  *(f32x4*)&part[w][0][lane * 4] = acc0;
  *(f32x4*)&part[w][1][lane * 4] = acc1;
  __syncthreads();
  if (tid < 128) {
    int r = tid >> 6, ll = tid & 63;
    int cf = ccl * 256 + ll * 4;
    f32x4 s = *(const f32x4*)&part[0][r][ll * 4];
    s += *(const f32x4*)&part[1][r][ll * 4];
    s += *(const f32x4*)&part[2][r][ll * 4];
    s += *(const f32x4*)&part[3][r][ll * 4];
    s += *(const f32x4*)&(is_gh ? bhh : bih)[cf];
    *(f32x4*)&(is_gh ? gh : gx)[(rg * 2 + r) * 1536 + cf] = s;
  }
}

// ---------------- GRU elementwise + LN -> hnew, hln ----------------
__global__ __launch_bounds__(512) void gru_ln_kernel(
    const float* __restrict__ gx, const float* __restrict__ gh,
    const float* __restrict__ slots,
    const float* __restrict__ lnf_g, const float* __restrict__ lnf_b,
    float* __restrict__ hnew, float* __restrict__ hln)
{
  __shared__ float red1[8], red2[8];
  int tid = threadIdx.x, row = blockIdx.x;
  float gxr = gx[row * 1536 + tid], gxz = gx[row * 1536 + 512 + tid], gxn = gx[row * 1536 + 1024 + tid];
  float ghr = gh[row * 1536 + tid], ghz = gh[row * 1536 + 512 + tid], ghn = gh[row * 1536 + 1024 + tid];
  float h = slots[row * 512 + tid];
  float r_ = 1.f / (1.f + __expf(-(gxr + ghr)));
  float z_ = 1.f / (1.f + __expf(-(gxz + ghz)));
  float n_ = tanhf(gxn + r_ * ghn);
  float hn = (1.f - z_) * n_ + z_ * h;
  hnew[row * 512 + tid] = hn;
  float s1 = wave_red_sum(hn), s2 = wave_red_sum(hn * hn);
  int w = tid >> 6, lane = tid & 63;
  if (lane == 0) { red1[w] = s1; red2[w] = s2; }
  __syncthreads();
  s1 = 0.f; s2 = 0.f;
#pragma unroll
  for (int i = 0; i < 8; ++i) { s1 += red1[i]; s2 += red2[i]; }
  float mean = s1 * (1.f / 512.f);
  float var = s2 * (1.f / 512.f) - mean * mean;
  float rstd = rsqrtf(var + LN_EPS);
  hln[row * 512 + tid] = (hn - mean) * rstd * lnf_g[tid] + lnf_b[tid];
}

// ---------------- mlp1: act = relu(hln @ W1 + b1) ----------------
__global__ __launch_bounds__(256) void mlp1_kernel(
    const float* __restrict__ hln, const float* __restrict__ W1,
    const float* __restrict__ b1, float* __restrict__ act)
{
  __shared__ float in_s[2][512];
  __shared__ float part[4][2][64];
  int tid = threadIdx.x, w = tid >> 6, lane = tid & 63;
  int rg = blockIdx.x >> 3, cc = blockIdx.x & 7;
  {
    int rr = tid >> 7, pos = (tid & 127) * 4;
    *(f32x4*)&in_s[rr][pos] = *(const f32x4*)&hln[(rg * 2 + rr) * 512 + pos];
  }
  __syncthreads();
  int c = cc * 64 + lane;
  float a0 = 0.f, a1 = 0.f;
  for (int d = w * 128; d < w * 128 + 128; ++d) {
    float wv = W1[d * 512 + c];
    a0 += in_s[0][d] * wv;
    a1 += in_s[1][d] * wv;
  }
  part[w][0][lane] = a0;
  part[w][1][lane] = a1;
  __syncthreads();
  if (tid < 128) {
    int r = tid >> 6, ll = tid & 63;
    float s = part[0][r][ll] + part[1][r][ll] + part[2][r][ll] + part[3][r][ll]
            + b1[cc * 64 + ll];
    act[(rg * 2 + r) * 512 + cc * 64 + ll] = fmaxf(s, 0.f);
  }
}

// ---------------- mlp2: slots = hnew + act @ W2 + b2 ----------------
__global__ __launch_bounds__(256) void mlp2_kernel(
    const float* __restrict__ act, const float* __restrict__ W2,
    const float* __restrict__ b2, const float* __restrict__ hnew,
    float* __restrict__ slots)
{
  __shared__ float in_s[2][512];
  __shared__ float part[4][2][64];
  int tid = threadIdx.x, w = tid >> 6, lane = tid & 63;
  int rg = blockIdx.x >> 3, cc = blockIdx.x & 7;
  {
    int rr = tid >> 7, pos = (tid & 127) * 4;
    *(f32x4*)&in_s[rr][pos] = *(const f32x4*)&act[(rg * 2 + rr) * 512 + pos];
  }
  __syncthreads();
  int c = cc * 64 + lane;
  float a0 = 0.f, a1 = 0.f;
  for (int d = w * 128; d < w * 128 + 128; ++d) {
    float wv = W2[d * 512 + c];
    a0 += in_s[0][d] * wv;
    a1 += in_s[1][d] * wv;
  }
  part[w][0][lane] = a0;
  part[w][1][lane] = a1;
  __syncthreads();
  if (tid < 128) {
    int r = tid >> 6, ll = tid & 63;
    int row = rg * 2 + r, c2 = cc * 64 + ll;
    float s = part[0][r][ll] + part[1][r][ll] + part[2][r][ll] + part[3][r][ll] + b2[c2];
    slots[row * 512 + c2] = hnew[row * 512 + c2] + s;
  }
}

// ---------------- attn normalize in place ----------------
__global__ __launch_bounds__(256) void norm_attn(
    const float* __restrict__ rowsum, float* __restrict__ attn)
{
  int idx = blockIdx.x * 256 + threadIdx.x;  // < 131072
  int row = idx >> 11;
  attn[idx] = attn[idx] / (rowsum[row] + EPS_);
}

extern "C" void kernel_launch(void* const* d_in, const int* in_sizes, int n_in,
                              void* d_out, int out_size, void* d_ws, size_t ws_size,
                              hipStream_t stream)
{
  const float* inputs     = (const float*)d_in[0];
  const float* slots_init = (const float*)d_in[1];
  const float* Wq   = (const float*)d_in[2];
  const float* bq   = (const float*)d_in[3];
  const float* Wk   = (const float*)d_in[4];
  const float* bk   = (const float*)d_in[5];
  const float* Wv   = (const float*)d_in[6];
  const float* bv   = (const float*)d_in[7];
  const float* ln_in_g = (const float*)d_in[8];
  const float* ln_in_b = (const float*)d_in[9];
  const float* ln_s_g  = (const float*)d_in[10];
  const float* ln_s_b  = (const float*)d_in[11];
  const float* ln_f_g  = (const float*)d_in[12];
  const float* ln_f_b  = (const float*)d_in[13];
  const float* wih  = (const float*)d_in[14];
  const float* whh  = (const float*)d_in[15];
  const float* bih  = (const float*)d_in[16];
  const float* bhh  = (const float*)d_in[17];
  const float* W1   = (const float*)d_in[18];
  const float* b1   = (const float*)d_in[19];
  const float* W2   = (const float*)d_in[20];
  const float* b2   = (const float*)d_in[21];

  float* out   = (float*)d_out;
  float* slots = out;                 // [32,2,512] working + final output
  float* q_out = out + 32768;         // [32,2,512]
  float* k_out = out + 65536;         // [32,2048,512] fp32 k (also read by attend)
  float* attnp = out + 33619968;      // [32,2,2048] attn (normalized at end)

  char* ws = (char*)d_ws;
  bf16_t* xbf   = (bf16_t*)(ws);                    // 67,108,864 LN(inputs) bf16
  bf16_t* vbf   = (bf16_t*)(ws + 67108864);         // 67,108,864
  bf16_t* BT    = (bf16_t*)(ws + 134217728);        //  1,048,576 (dead after gemm)
  float*  gx    = (float*)(ws + 134217728);         //    393,216 (alias)
  float*  gh    = (float*)(ws + 134610944);         //    393,216
  float*  hnew  = (float*)(ws + 135004160);         //    131,072
  float*  hln   = (float*)(ws + 135135232);         //    131,072
  float*  wihT  = (float*)(ws + 135266304);         //  3,145,728
  float*  whhT  = (float*)(ws + 138412032);         //  3,145,728
  float*  biasc = (float*)(ws + 141557760);         //      4,096
  float*  act   = (float*)(ws + 141561856);         //    131,072
  float*  upd   = (float*)(ws + 142086144);         //    131,072
  float*  rowsum= (float*)(ws + 142217216);         //        256  -> end 142,217,472

  transpose_prep<<<dim3(16, 48, 4), 256, 0, stream>>>(Wk, Wv, wih, whh, BT, wihT, whhT);
  small_prep<<<132, 256, 0, stream>>>(bk, bv, slots_init, biasc, slots);
  ln_apply<<<16384, 256, 0, stream>>>(inputs, ln_in_g, ln_in_b, xbf);
  gemm_kv<<<4096, 256, 0, stream>>>(xbf, BT, biasc, k_out, vbf);
  for (int it = 0; it < 3; ++it) {
    hipMemsetAsync(upd, 0, 131072 + 256, stream);  // zero upd + rowsum
    ln_q_kernel<<<32, 256, 0, stream>>>(slots, ln_s_g, ln_s_b, Wq, bq, q_out);
    attend_fused<<<1024, 256, 0, stream>>>(k_out, vbf, q_out, upd, rowsum, attnp);
    gates_kernel<<<384, 256, 0, stream>>>(slots, upd, rowsum, wihT, whhT, bih, bhh, gx, gh);
    gru_ln_kernel<<<64, 512, 0, stream>>>(gx, gh, slots, ln_f_g, ln_f_b, hnew, hln);
    mlp1_kernel<<<256, 256, 0, stream>>>(hln, W1, b1, act);
    mlp2_kernel<<<256, 256, 0, stream>>>(act, W2, b2, hnew, slots);
  }
  norm_attn<<<512, 256, 0, stream>>>(rowsum, attnp);
}

// Round 5
// 648.971 us; speedup vs baseline: 1.5026x; 1.5026x over previous
//
#include <hip/hip_runtime.h>
#include <stdint.h>

typedef __bf16 bf16_t;
typedef bf16_t bf16x8 __attribute__((ext_vector_type(8)));
typedef float f32x4 __attribute__((ext_vector_type(4)));

typedef unsigned int u32;
typedef __attribute__((address_space(1))) const u32 gu32;
typedef __attribute__((address_space(3))) u32 lu32;

#define LN_EPS 1e-5f
#define EPS_ 1e-8f
#define SCALE_ 0.04419417382415922f  // 512^-0.5

__device__ __forceinline__ float wave_red_sum(float v) {
#pragma unroll
  for (int off = 32; off > 0; off >>= 1) v += __shfl_xor(v, off, 64);
  return v;
}

// ---------------- prep: LDS-tiled transposes (coalesced both sides) ----------------
__global__ __launch_bounds__(256) void transpose_prep(
    const float* __restrict__ Wk, const float* __restrict__ Wv,
    const float* __restrict__ wih, const float* __restrict__ whh,
    bf16_t* __restrict__ BT, float* __restrict__ wihT, float* __restrict__ whhT)
{
  int z = blockIdx.z;
  if (z < 2 && blockIdx.y >= 16) return;
  const float* src = (z == 0) ? Wk : (z == 1) ? Wv : (z == 2) ? wih : whh;
  __shared__ float tile[32][33];
  int tx = threadIdx.x & 31, ty = threadIdx.x >> 5;  // 32 x 8
  int row0 = blockIdx.y * 32, col0 = blockIdx.x * 32;
#pragma unroll
  for (int i = 0; i < 4; ++i)
    tile[ty + 8 * i][tx] = src[(size_t)(row0 + ty + 8 * i) * 512 + col0 + tx];
  __syncthreads();
  if (z < 2) {
#pragma unroll
    for (int i = 0; i < 4; ++i)
      BT[(size_t)(z * 512 + col0 + ty + 8 * i) * 512 + row0 + tx] =
          (bf16_t)tile[tx][ty + 8 * i];
  } else {
    float* dst = (z == 2) ? wihT : whhT;
#pragma unroll
    for (int i = 0; i < 4; ++i)
      dst[(size_t)(col0 + ty + 8 * i) * 1536 + row0 + tx] = tile[tx][ty + 8 * i];
  }
}

// ---------------- small prep: biasc pack + slots init (into d_out) ----------------
__global__ __launch_bounds__(256) void small_prep(
    const float* __restrict__ bk, const float* __restrict__ bv,
    const float* __restrict__ slots_init,
    float* __restrict__ biasc, float* __restrict__ slots)
{
  int idx = blockIdx.x * 256 + threadIdx.x;  // < 33792
  if (idx < 1024) {
    biasc[idx] = (idx < 512) ? bk[idx] : bv[idx - 512];
  } else {
    int i = idx - 1024;  // < 32768
    slots[i] = slots_init[i];
  }
}

// ---------------- LN(inputs) -> bf16, one wave per row ----------------
__global__ __launch_bounds__(256) void ln_apply(
    const float* __restrict__ in, const float* __restrict__ lng,
    const float* __restrict__ lnb, bf16_t* __restrict__ xbf)
{
  int w = threadIdx.x >> 6, lane = threadIdx.x & 63;
  size_t row = (size_t)blockIdx.x * 4 + w;
  const float4* rp = (const float4*)(in + row * 512);
  float4 a = rp[lane * 2], c = rp[lane * 2 + 1];
  float s1 = a.x + a.y + a.z + a.w + c.x + c.y + c.z + c.w;
  float s2 = a.x * a.x + a.y * a.y + a.z * a.z + a.w * a.w +
             c.x * c.x + c.y * c.y + c.z * c.z + c.w * c.w;
  s1 = wave_red_sum(s1);
  s2 = wave_red_sum(s2);
  float mean = s1 * (1.f / 512.f);
  float var = s2 * (1.f / 512.f) - mean * mean;
  float rs = rsqrtf(var + LN_EPS);
  float4 g0 = *(const float4*)&lng[lane * 8];
  float4 g1 = *(const float4*)&lng[lane * 8 + 4];
  float4 b0 = *(const float4*)&lnb[lane * 8];
  float4 b1 = *(const float4*)&lnb[lane * 8 + 4];
  bf16x8 o;
  o[0] = (bf16_t)((a.x - mean) * rs * g0.x + b0.x);
  o[1] = (bf16_t)((a.y - mean) * rs * g0.y + b0.y);
  o[2] = (bf16_t)((a.z - mean) * rs * g0.z + b0.z);
  o[3] = (bf16_t)((a.w - mean) * rs * g0.w + b0.w);
  o[4] = (bf16_t)((c.x - mean) * rs * g1.x + b1.x);
  o[5] = (bf16_t)((c.y - mean) * rs * g1.y + b1.y);
  o[6] = (bf16_t)((c.z - mean) * rs * g1.z + b1.z);
  o[7] = (bf16_t)((c.w - mean) * rs * g1.w + b1.w);
  *(bf16x8*)&xbf[row * 512 + lane * 8] = o;
}

// ---------------- pure bf16 MFMA GEMM, XCD-swizzled, swizzled LDS ----------------
__global__ __launch_bounds__(256) void gemm_kv(
    const bf16_t* __restrict__ xbf, const bf16_t* __restrict__ BT,
    const float* __restrict__ biasc,
    float* __restrict__ out_k, bf16_t* __restrict__ vbf)
{
  __shared__ __align__(16) char smem[16384];
  bf16_t* As = (bf16_t*)smem;             // 128 x 32 bf16 (swizzled granules)
  bf16_t* Bs = (bf16_t*)(smem + 8192);    // 128 x 32 bf16 (swizzled granules)
  float (*Cs)[132] = (float(*)[132])smem; // 16 x 132 fp32 (epilogue reuse)

  const int tid = threadIdx.x, lane = tid & 63, w = tid >> 6;
  const int quad = lane >> 4, l16 = lane & 15;
  const int l = blockIdx.x;
  const int x = l & 7, t = l >> 3;
  const int n0 = (t & 7) * 128;
  const int m0 = ((t >> 3) * 8 + x) * 128;
  const int mb = (w & 1) * 64, nb = (w >> 1) * 64;
  const int swz = (l16 >> 1) & 3;

  const bf16_t* a_base = xbf + (size_t)m0 * 512;
  const bf16_t* b_base = BT + (size_t)n0 * 512;

  f32x4 acc[4][4] = {};

  for (int kk = 0; kk < 512; kk += 32) {
#pragma unroll
    for (int r = 0; r < 2; ++r) {
      int tt = tid + r * 256;
      int rr = tt >> 2, pg = tt & 3;
      int lg = pg ^ ((rr >> 1) & 3);  // pre-swizzled source granule
      __builtin_amdgcn_global_load_lds((gu32*)(a_base + (size_t)rr * 512 + kk + lg * 8),
                                       (lu32*)&As[tt * 8], 16, 0, 0);
      __builtin_amdgcn_global_load_lds((gu32*)(b_base + (size_t)rr * 512 + kk + lg * 8),
                                       (lu32*)&Bs[tt * 8], 16, 0, 0);
    }
    __syncthreads();
    bf16x8 af[4], bfr[4];
#pragma unroll
    for (int mt = 0; mt < 4; ++mt)
      af[mt] = *(const bf16x8*)&As[(mb + mt * 16 + l16) * 32 + (quad ^ swz) * 8];
#pragma unroll
    for (int nt = 0; nt < 4; ++nt)
      bfr[nt] = *(const bf16x8*)&Bs[(nb + nt * 16 + l16) * 32 + (quad ^ swz) * 8];
#pragma unroll
    for (int mt = 0; mt < 4; ++mt)
#pragma unroll
      for (int nt = 0; nt < 4; ++nt)
        acc[mt][nt] = __builtin_amdgcn_mfma_f32_16x16x32_bf16(af[mt], bfr[nt], acc[mt][nt], 0, 0, 0);
    __syncthreads();
  }

  const int is_k = (n0 < 512);
  const int col4 = (tid * 4) & 127;
  const int row8 = tid >> 4;
  const int col8 = (tid * 8) & 127;
  for (int ci = 0; ci < 8; ++ci) {
    if ((ci < 4) == (mb == 0)) {
      int mt = ci & 3;
#pragma unroll
      for (int nt = 0; nt < 4; ++nt)
#pragma unroll
        for (int r = 0; r < 4; ++r)
          Cs[quad * 4 + r][nb + nt * 16 + l16] = acc[mt][nt][r];
    }
    __syncthreads();
    int rowbase = m0 + ci * 16;
    if (is_k) {
      f32x4 bias4 = *(const f32x4*)&biasc[n0 + col4];
#pragma unroll
      for (int p = 0; p < 2; ++p) {
        int f = p * 1024 + tid * 4;
        int row = f >> 7;
        f32x4 v = *(const f32x4*)&Cs[row][col4] + bias4;
        *(f32x4*)&out_k[(size_t)(rowbase + row) * 512 + n0 + col4] = v;
      }
    } else {
      f32x4 ba = *(const f32x4*)&biasc[n0 + col8];
      f32x4 bb = *(const f32x4*)&biasc[n0 + col8 + 4];
      f32x4 v0 = *(const f32x4*)&Cs[row8][col8] + ba;
      f32x4 v1 = *(const f32x4*)&Cs[row8][col8 + 4] + bb;
      bf16x8 o;
#pragma unroll
      for (int j = 0; j < 4; ++j) { o[j] = (bf16_t)v0[j]; o[4 + j] = (bf16_t)v1[j]; }
      *(bf16x8*)&vbf[(size_t)(rowbase + row8) * 512 + (n0 - 512) + col8] = o;
    }
    __syncthreads();
  }
}

// ---------------- ln_q v2: LN(slots) + q GEMV, mlp1-style split ----------------
// grid 256 = 32 b x 8 col-groups of 64; waves split K, LDS reduce.
__global__ __launch_bounds__(256) void ln_q_kernel(
    const float* __restrict__ slots,
    const float* __restrict__ lnsg, const float* __restrict__ lnsb,
    const float* __restrict__ Wq, const float* __restrict__ bq,
    float* __restrict__ q_out)
{
  __shared__ float s[2][512];
  __shared__ float part[4][2][64];
  __shared__ float red1[4], red2[4];
  int tid = threadIdx.x, w = tid >> 6, lane = tid & 63;
  int b = blockIdx.x >> 3, cg = blockIdx.x & 7;

  int r = tid >> 7;
  int off = (tid * 4) & 511;
  float4 v = *(const float4*)&slots[b * 1024 + tid * 4];
  float s1 = v.x + v.y + v.z + v.w;
  float s2 = v.x * v.x + v.y * v.y + v.z * v.z + v.w * v.w;
  s1 = wave_red_sum(s1);
  s2 = wave_red_sum(s2);
  if (lane == 0) { red1[w] = s1; red2[w] = s2; }
  __syncthreads();
  float mean = (red1[r * 2] + red1[r * 2 + 1]) * (1.f / 512.f);
  float var = (red2[r * 2] + red2[r * 2 + 1]) * (1.f / 512.f) - mean * mean;
  float rstd = rsqrtf(var + LN_EPS);
  float4 g4 = *(const float4*)&lnsg[off];
  float4 b4 = *(const float4*)&lnsb[off];
  s[r][off + 0] = (v.x - mean) * rstd * g4.x + b4.x;
  s[r][off + 1] = (v.y - mean) * rstd * g4.y + b4.y;
  s[r][off + 2] = (v.z - mean) * rstd * g4.z + b4.z;
  s[r][off + 3] = (v.w - mean) * rstd * g4.w + b4.w;
  __syncthreads();

  int c = cg * 64 + lane;
  float a0 = 0.f, a1 = 0.f;
  for (int d = w * 128; d < w * 128 + 128; ++d) {
    float wv = Wq[d * 512 + c];
    a0 += s[0][d] * wv;
    a1 += s[1][d] * wv;
  }
  part[w][0][lane] = a0;
  part[w][1][lane] = a1;
  __syncthreads();
  if (tid < 128) {
    int rr = tid >> 6, ll = tid & 63;
    float sum = part[0][rr][ll] + part[1][rr][ll] + part[2][rr][ll] + part[3][rr][ll]
              + bq[cg * 64 + ll];
    q_out[(b * 2 + rr) * 512 + cg * 64 + ll] = sum;
  }
}

// ---------------- attend v3: per-lane-j dots, NO global atomics ----------------
// grid 1024 = 32 b x 32 chunks of 64 j. Each wave stores its update partial
// (over its 16 j's) to upd_part[chunk*4+w][row][512]; per-chunk rowsum partial
// to rs_part[row][chunk]. reduce_upd sums them afterwards.
__global__ __launch_bounds__(256) void attend_fused(
    const float* __restrict__ kf, const bf16_t* __restrict__ vbf,
    const float* __restrict__ qf,
    float* __restrict__ upd_part, float* __restrict__ rs_part,
    float* __restrict__ attn_pre)
{
  __shared__ float qs[2][528];   // [slot][dq*132 + dd] -- pitched
  __shared__ float p_s[2][64];
  int tid = threadIdx.x, w = tid >> 6, lane = tid & 63;
  int b = blockIdx.x >> 5, chunk = blockIdx.x & 31;
  int j0 = chunk * 64;

  // stage q[2][512] into LDS (pitched)
  {
    int slot = tid >> 7, pos = (tid & 127) * 4;
    int dq = pos >> 7, dd = pos & 127;
    *(f32x4*)&qs[slot][dq * 132 + dd] = *(const f32x4*)&qf[b * 1024 + slot * 512 + pos];
  }
  __syncthreads();

  // ---- phase 1: dots + softmax over slots, per-lane ----
  int jj = lane & 15;           // j within wave's 16
  int dq = lane >> 4;           // d quarter
  const float* kp = kf + (size_t)(b * 2048 + j0 + w * 16 + jj) * 512 + dq * 128;
  const float* qb0 = &qs[0][dq * 132];
  const float* qb1 = &qs[1][dq * 132];
  float dot0 = 0.f, dot1 = 0.f;
#pragma unroll
  for (int h = 0; h < 4; ++h) {
    f32x4 kr[8];
#pragma unroll
    for (int i = 0; i < 8; ++i) kr[i] = *(const f32x4*)(kp + h * 32 + i * 4);
#pragma unroll
    for (int i = 0; i < 8; ++i) {
      f32x4 qa = *(const f32x4*)(qb0 + h * 32 + i * 4);
      f32x4 qc = *(const f32x4*)(qb1 + h * 32 + i * 4);
#pragma unroll
      for (int t = 0; t < 4; ++t) {
        dot0 += kr[i][t] * qa[t];
        dot1 += kr[i][t] * qc[t];
      }
    }
  }
  // combine the 4 d-quarters (lanes differing in bits 4,5)
  dot0 += __shfl_xor(dot0, 16, 64);
  dot0 += __shfl_xor(dot0, 32, 64);
  dot1 += __shfl_xor(dot1, 16, 64);
  dot1 += __shfl_xor(dot1, 32, 64);
  float d0f = dot0 * SCALE_, d1f = dot1 * SCALE_;
  float mx = fmaxf(d0f, d1f);
  float e0 = __expf(d0f - mx), e1 = __expf(d1f - mx);
  float inv = 1.f / (e0 + e1);
  float p0 = e0 * inv, p1 = e1 * inv;
  if (lane < 16) {
    int jj2 = w * 16 + lane;
    p_s[0][jj2] = p0;
    p_s[1][jj2] = p1;
    attn_pre[(b * 2 + 0) * 2048 + j0 + jj2] = p0;
    attn_pre[(b * 2 + 1) * 2048 + j0 + jj2] = p1;
  }
  __syncthreads();

  // rowsum partials: wave 0 reduces the block's 64 p's per slot
  if (w == 0) {
    float a = p_s[0][lane];
    float c = p_s[1][lane];
    a = wave_red_sum(a);
    c = wave_red_sum(c);
    if (lane == 0) {
      rs_part[(b * 2 + 0) * 32 + chunk] = a;
      rs_part[(b * 2 + 1) * 32 + chunk] = c;
    }
  }

  // ---- phase 2: weighted-v accumulate over this wave's 16 j's ----
  float u0[8] = {}, u1[8] = {};
  const bf16_t* vp = vbf + (size_t)(b * 2048 + j0 + w * 16) * 512 + lane * 8;
  for (int t = 0; t < 16; ++t) {
    float p0b = p_s[0][w * 16 + t];
    float p1b = p_s[1][w * 16 + t];
    bf16x8 vv = *(const bf16x8*)(vp + (size_t)t * 512);
#pragma unroll
    for (int tt = 0; tt < 8; ++tt) {
      float vfl = (float)vv[tt];
      u0[tt] += p0b * vfl;
      u1[tt] += p1b * vfl;
    }
  }
  // coalesced partial stores (race-free: one wave per (part, row))
  float* up0 = upd_part + ((size_t)(chunk * 4 + w) * 64 + b * 2 + 0) * 512 + lane * 8;
  f32x4 w0a = {u0[0], u0[1], u0[2], u0[3]}, w0b = {u0[4], u0[5], u0[6], u0[7]};
  f32x4 w1a = {u1[0], u1[1], u1[2], u1[3]}, w1b = {u1[4], u1[5], u1[6], u1[7]};
  *(f32x4*)(up0) = w0a;
  *(f32x4*)(up0 + 4) = w0b;
  *(f32x4*)(up0 + 512) = w1a;
  *(f32x4*)(up0 + 516) = w1b;
}

// ---------------- reduce_upd: sum 128 partials -> upd, rowsum ----------------
// grid 64 (one block per row), 512 threads (one per col)
__global__ __launch_bounds__(512) void reduce_upd(
    const float* __restrict__ upd_part, const float* __restrict__ rs_part,
    float* __restrict__ upd, float* __restrict__ rowsum)
{
  int r = blockIdx.x, tid = threadIdx.x;
  const float* p = upd_part + (size_t)r * 512 + tid;
  float acc = 0.f;
#pragma unroll 8
  for (int i = 0; i < 128; ++i) acc += p[(size_t)i * 32768];
  upd[r * 512 + tid] = acc;
  if (tid < 64) {
    float v = (tid < 32) ? rs_part[r * 32 + tid] : 0.f;
    v = wave_red_sum(v);
    if (tid == 0) rowsum[r] = v;
  }
}

// ---------------- gates: gx = u@wihT + bih, gh = h@whhT + bhh ----------------
__global__ __launch_bounds__(256) void gates_kernel(
    const float* __restrict__ slots, const float* __restrict__ upd,
    const float* __restrict__ rowsum,
    const float* __restrict__ wihT, const float* __restrict__ whhT,
    const float* __restrict__ bih, const float* __restrict__ bhh,
    float* __restrict__ gx, float* __restrict__ gh)
{
  __shared__ float in_s[2][512];
  __shared__ float part[4][2][256];
  int tid = threadIdx.x, w = tid >> 6, lane = tid & 63;
  int rg = blockIdx.x / 12, cc = blockIdx.x % 12;
  int is_gh = (cc >= 6);
  int ccl = is_gh ? cc - 6 : cc;
  {
    int rr = tid >> 7, pos = (tid & 127) * 4;
    int row = rg * 2 + rr;
    const float* src = (is_gh ? slots : upd) + row * 512;
    f32x4 v = *(const f32x4*)&src[pos];
    if (!is_gh) v *= 1.f / (rowsum[row] + EPS_);
    *(f32x4*)&in_s[rr][pos] = v;
  }
  __syncthreads();
  int c0 = ccl * 256 + lane * 4;
  const float* __restrict__ W = is_gh ? whhT : wihT;
  f32x4 acc0 = {0.f, 0.f, 0.f, 0.f}, acc1 = acc0;
  for (int d = w * 128; d < w * 128 + 128; ++d) {
    f32x4 w4 = *(const f32x4*)&W[d * 1536 + c0];
    acc0 += in_s[0][d] * w4;
    acc1 += in_s[1][d] * w4;
  }
  *(f32x4*)&part[w][0][lane * 4] = acc0;
  *(f32x4*)&part[w][1][lane * 4] = acc1;
  __syncthreads();
  if (tid < 128) {
    int r = tid >> 6, ll = tid & 63;
    int cf = ccl * 256 + ll * 4;
    f32x4 s = *(const f32x4*)&part[0][r][ll * 4];
    s += *(const f32x4*)&part[1][r][ll * 4];
    s += *(const f32x4*)&part[2][r][ll * 4];
    s += *(const f32x4*)&part[3][r][ll * 4];
    s += *(const f32x4*)&(is_gh ? bhh : bih)[cf];
    *(f32x4*)&(is_gh ? gh : gx)[(rg * 2 + r) * 1536 + cf] = s;
  }
}

// ---------------- GRU elementwise + LN -> hnew, hln ----------------
__global__ __launch_bounds__(512) void gru_ln_kernel(
    const float* __restrict__ gx, const float* __restrict__ gh,
    const float* __restrict__ slots,
    const float* __restrict__ lnf_g, const float* __restrict__ lnf_b,
    float* __restrict__ hnew, float* __restrict__ hln)
{
  __shared__ float red1[8], red2[8];
  int tid = threadIdx.x, row = blockIdx.x;
  float gxr = gx[row * 1536 + tid], gxz = gx[row * 1536 + 512 + tid], gxn = gx[row * 1536 + 1024 + tid];
  float ghr = gh[row * 1536 + tid], ghz = gh[row * 1536 + 512 + tid], ghn = gh[row * 1536 + 1024 + tid];
  float h = slots[row * 512 + tid];
  float r_ = 1.f / (1.f + __expf(-(gxr + ghr)));
  float z_ = 1.f / (1.f + __expf(-(gxz + ghz)));
  float n_ = tanhf(gxn + r_ * ghn);
  float hn = (1.f - z_) * n_ + z_ * h;
  hnew[row * 512 + tid] = hn;
  float s1 = wave_red_sum(hn), s2 = wave_red_sum(hn * hn);
  int w = tid >> 6, lane = tid & 63;
  if (lane == 0) { red1[w] = s1; red2[w] = s2; }
  __syncthreads();
  s1 = 0.f; s2 = 0.f;
#pragma unroll
  for (int i = 0; i < 8; ++i) { s1 += red1[i]; s2 += red2[i]; }
  float mean = s1 * (1.f / 512.f);
  float var = s2 * (1.f / 512.f) - mean * mean;
  float rstd = rsqrtf(var + LN_EPS);
  hln[row * 512 + tid] = (hn - mean) * rstd * lnf_g[tid] + lnf_b[tid];
}

// ---------------- mlp1: act = relu(hln @ W1 + b1) ----------------
__global__ __launch_bounds__(256) void mlp1_kernel(
    const float* __restrict__ hln, const float* __restrict__ W1,
    const float* __restrict__ b1, float* __restrict__ act)
{
  __shared__ float in_s[2][512];
  __shared__ float part[4][2][64];
  int tid = threadIdx.x, w = tid >> 6, lane = tid & 63;
  int rg = blockIdx.x >> 3, cc = blockIdx.x & 7;
  {
    int rr = tid >> 7, pos = (tid & 127) * 4;
    *(f32x4*)&in_s[rr][pos] = *(const f32x4*)&hln[(rg * 2 + rr) * 512 + pos];
  }
  __syncthreads();
  int c = cc * 64 + lane;
  float a0 = 0.f, a1 = 0.f;
  for (int d = w * 128; d < w * 128 + 128; ++d) {
    float wv = W1[d * 512 + c];
    a0 += in_s[0][d] * wv;
    a1 += in_s[1][d] * wv;
  }
  part[w][0][lane] = a0;
  part[w][1][lane] = a1;
  __syncthreads();
  if (tid < 128) {
    int r = tid >> 6, ll = tid & 63;
    float s = part[0][r][ll] + part[1][r][ll] + part[2][r][ll] + part[3][r][ll]
            + b1[cc * 64 + ll];
    act[(rg * 2 + r) * 512 + cc * 64 + ll] = fmaxf(s, 0.f);
  }
}

// ---------------- mlp2: slots = hnew + act @ W2 + b2 ----------------
__global__ __launch_bounds__(256) void mlp2_kernel(
    const float* __restrict__ act, const float* __restrict__ W2,
    const float* __restrict__ b2, const float* __restrict__ hnew,
    float* __restrict__ slots)
{
  __shared__ float in_s[2][512];
  __shared__ float part[4][2][64];
  int tid = threadIdx.x, w = tid >> 6, lane = tid & 63;
  int rg = blockIdx.x >> 3, cc = blockIdx.x & 7;
  {
    int rr = tid >> 7, pos = (tid & 127) * 4;
    *(f32x4*)&in_s[rr][pos] = *(const f32x4*)&act[(rg * 2 + rr) * 512 + pos];
  }
  __syncthreads();
  int c = cc * 64 + lane;
  float a0 = 0.f, a1 = 0.f;
  for (int d = w * 128; d < w * 128 + 128; ++d) {
    float wv = W2[d * 512 + c];
    a0 += in_s[0][d] * wv;
    a1 += in_s[1][d] * wv;
  }
  part[w][0][lane] = a0;
  part[w][1][lane] = a1;
  __syncthreads();
  if (tid < 128) {
    int r = tid >> 6, ll = tid & 63;
    int row = rg * 2 + r, c2 = cc * 64 + ll;
    float s = part[0][r][ll] + part[1][r][ll] + part[2][r][ll] + part[3][r][ll] + b2[c2];
    slots[row * 512 + c2] = hnew[row * 512 + c2] + s;
  }
}

// ---------------- attn normalize in place ----------------
__global__ __launch_bounds__(256) void norm_attn(
    const float* __restrict__ rowsum, float* __restrict__ attn)
{
  int idx = blockIdx.x * 256 + threadIdx.x;  // < 131072
  int row = idx >> 11;
  attn[idx] = attn[idx] / (rowsum[row] + EPS_);
}

extern "C" void kernel_launch(void* const* d_in, const int* in_sizes, int n_in,
                              void* d_out, int out_size, void* d_ws, size_t ws_size,
                              hipStream_t stream)
{
  const float* inputs     = (const float*)d_in[0];
  const float* slots_init = (const float*)d_in[1];
  const float* Wq   = (const float*)d_in[2];
  const float* bq   = (const float*)d_in[3];
  const float* Wk   = (const float*)d_in[4];
  const float* bk   = (const float*)d_in[5];
  const float* Wv   = (const float*)d_in[6];
  const float* bv   = (const float*)d_in[7];
  const float* ln_in_g = (const float*)d_in[8];
  const float* ln_in_b = (const float*)d_in[9];
  const float* ln_s_g  = (const float*)d_in[10];
  const float* ln_s_b  = (const float*)d_in[11];
  const float* ln_f_g  = (const float*)d_in[12];
  const float* ln_f_b  = (const float*)d_in[13];
  const float* wih  = (const float*)d_in[14];
  const float* whh  = (const float*)d_in[15];
  const float* bih  = (const float*)d_in[16];
  const float* bhh  = (const float*)d_in[17];
  const float* W1   = (const float*)d_in[18];
  const float* b1   = (const float*)d_in[19];
  const float* W2   = (const float*)d_in[20];
  const float* b2   = (const float*)d_in[21];

  float* out   = (float*)d_out;
  float* slots = out;                 // [32,2,512] working + final output
  float* q_out = out + 32768;         // [32,2,512]
  float* k_out = out + 65536;         // [32,2048,512] fp32 k (read by attend)
  float* attnp = out + 33619968;      // [32,2,2048] attn (normalized at end)

  char* ws = (char*)d_ws;
  bf16_t* xbf   = (bf16_t*)(ws);                    // 67,108,864 LN(inputs) bf16 (dead after gemm)
  float*  upd_part = (float*)(ws);                  // 16,777,216 (alias xbf; live in iters)
  float*  rs_part  = (float*)(ws + 16777216);       //      8,192 (alias xbf)
  bf16_t* vbf   = (bf16_t*)(ws + 67108864);         // 67,108,864
  bf16_t* BT    = (bf16_t*)(ws + 134217728);        //  1,048,576 (dead after gemm)
  float*  gx    = (float*)(ws + 134217728);         //    393,216 (alias)
  float*  gh    = (float*)(ws + 134610944);         //    393,216
  float*  hnew  = (float*)(ws + 135004160);         //    131,072
  float*  hln   = (float*)(ws + 135135232);         //    131,072
  float*  wihT  = (float*)(ws + 135266304);         //  3,145,728
  float*  whhT  = (float*)(ws + 138412032);         //  3,145,728
  float*  biasc = (float*)(ws + 141557760);         //      4,096
  float*  act   = (float*)(ws + 141561856);         //    131,072
  float*  upd   = (float*)(ws + 142086144);         //    131,072
  float*  rowsum= (float*)(ws + 142217216);         //        256  -> end 142,217,472

  transpose_prep<<<dim3(16, 48, 4), 256, 0, stream>>>(Wk, Wv, wih, whh, BT, wihT, whhT);
  small_prep<<<132, 256, 0, stream>>>(bk, bv, slots_init, biasc, slots);
  ln_apply<<<16384, 256, 0, stream>>>(inputs, ln_in_g, ln_in_b, xbf);
  gemm_kv<<<4096, 256, 0, stream>>>(xbf, BT, biasc, k_out, vbf);
  for (int it = 0; it < 3; ++it) {
    ln_q_kernel<<<256, 256, 0, stream>>>(slots, ln_s_g, ln_s_b, Wq, bq, q_out);
    attend_fused<<<1024, 256, 0, stream>>>(k_out, vbf, q_out, upd_part, rs_part, attnp);
    reduce_upd<<<64, 512, 0, stream>>>(upd_part, rs_part, upd, rowsum);
    gates_kernel<<<384, 256, 0, stream>>>(slots, upd, rowsum, wihT, whhT, bih, bhh, gx, gh);
    gru_ln_kernel<<<64, 512, 0, stream>>>(gx, gh, slots, ln_f_g, ln_f_b, hnew, hln);
    mlp1_kernel<<<256, 256, 0, stream>>>(hln, W1, b1, act);
    mlp2_kernel<<<256, 256, 0, stream>>>(act, W2, b2, hnew, slots);
  }
  norm_attn<<<512, 256, 0, stream>>>(rowsum, attnp);
}

// Round 6
// 635.568 us; speedup vs baseline: 1.5343x; 1.0211x over previous
//
#include <hip/hip_runtime.h>
#include <stdint.h>

typedef __bf16 bf16_t;
typedef bf16_t bf16x8 __attribute__((ext_vector_type(8)));
typedef float f32x4 __attribute__((ext_vector_type(4)));

typedef unsigned int u32;
typedef __attribute__((address_space(1))) const u32 gu32;
typedef __attribute__((address_space(3))) u32 lu32;

#define LN_EPS 1e-5f
#define EPS_ 1e-8f
#define SCALE_ 0.04419417382415922f  // 512^-0.5

__device__ __forceinline__ float wave_red_sum(float v) {
#pragma unroll
  for (int off = 32; off > 0; off >>= 1) v += __shfl_xor(v, off, 64);
  return v;
}

// ---------------- prep: LDS-tiled transposes (coalesced both sides) ----------------
__global__ __launch_bounds__(256) void transpose_prep(
    const float* __restrict__ Wk, const float* __restrict__ Wv,
    const float* __restrict__ wih, const float* __restrict__ whh,
    bf16_t* __restrict__ BT, float* __restrict__ wihT, float* __restrict__ whhT)
{
  int z = blockIdx.z;
  if (z < 2 && blockIdx.y >= 16) return;
  const float* src = (z == 0) ? Wk : (z == 1) ? Wv : (z == 2) ? wih : whh;
  __shared__ float tile[32][33];
  int tx = threadIdx.x & 31, ty = threadIdx.x >> 5;  // 32 x 8
  int row0 = blockIdx.y * 32, col0 = blockIdx.x * 32;
#pragma unroll
  for (int i = 0; i < 4; ++i)
    tile[ty + 8 * i][tx] = src[(size_t)(row0 + ty + 8 * i) * 512 + col0 + tx];
  __syncthreads();
  if (z < 2) {
#pragma unroll
    for (int i = 0; i < 4; ++i)
      BT[(size_t)(z * 512 + col0 + ty + 8 * i) * 512 + row0 + tx] =
          (bf16_t)tile[tx][ty + 8 * i];
  } else {
    float* dst = (z == 2) ? wihT : whhT;
#pragma unroll
    for (int i = 0; i < 4; ++i)
      dst[(size_t)(col0 + ty + 8 * i) * 1536 + row0 + tx] = tile[tx][ty + 8 * i];
  }
}

// ---------------- small prep: biasc pack + slots init (into d_out) ----------------
__global__ __launch_bounds__(256) void small_prep(
    const float* __restrict__ bk, const float* __restrict__ bv,
    const float* __restrict__ slots_init,
    float* __restrict__ biasc, float* __restrict__ slots)
{
  int idx = blockIdx.x * 256 + threadIdx.x;  // < 33792
  if (idx < 1024) {
    biasc[idx] = (idx < 512) ? bk[idx] : bv[idx - 512];
  } else {
    int i = idx - 1024;  // < 32768
    slots[i] = slots_init[i];
  }
}

// ---------------- LN(inputs) -> bf16, one wave per row ----------------
__global__ __launch_bounds__(256) void ln_apply(
    const float* __restrict__ in, const float* __restrict__ lng,
    const float* __restrict__ lnb, bf16_t* __restrict__ xbf)
{
  int w = threadIdx.x >> 6, lane = threadIdx.x & 63;
  size_t row = (size_t)blockIdx.x * 4 + w;
  const float4* rp = (const float4*)(in + row * 512);
  float4 a = rp[lane * 2], c = rp[lane * 2 + 1];
  float s1 = a.x + a.y + a.z + a.w + c.x + c.y + c.z + c.w;
  float s2 = a.x * a.x + a.y * a.y + a.z * a.z + a.w * a.w +
             c.x * c.x + c.y * c.y + c.z * c.z + c.w * c.w;
  s1 = wave_red_sum(s1);
  s2 = wave_red_sum(s2);
  float mean = s1 * (1.f / 512.f);
  float var = s2 * (1.f / 512.f) - mean * mean;
  float rs = rsqrtf(var + LN_EPS);
  float4 g0 = *(const float4*)&lng[lane * 8];
  float4 g1 = *(const float4*)&lng[lane * 8 + 4];
  float4 b0 = *(const float4*)&lnb[lane * 8];
  float4 b1 = *(const float4*)&lnb[lane * 8 + 4];
  bf16x8 o;
  o[0] = (bf16_t)((a.x - mean) * rs * g0.x + b0.x);
  o[1] = (bf16_t)((a.y - mean) * rs * g0.y + b0.y);
  o[2] = (bf16_t)((a.z - mean) * rs * g0.z + b0.z);
  o[3] = (bf16_t)((a.w - mean) * rs * g0.w + b0.w);
  o[4] = (bf16_t)((c.x - mean) * rs * g1.x + b1.x);
  o[5] = (bf16_t)((c.y - mean) * rs * g1.y + b1.y);
  o[6] = (bf16_t)((c.z - mean) * rs * g1.z + b1.z);
  o[7] = (bf16_t)((c.w - mean) * rs * g1.w + b1.w);
  *(bf16x8*)&xbf[row * 512 + lane * 8] = o;
}

// ---------------- pure bf16 MFMA GEMM, BK=64, XCD-swizzled, 8-granule XOR LDS ----------------
// optional kbf output (bf16 copy of k) when workspace allows
__global__ __launch_bounds__(256) void gemm_kv(
    const bf16_t* __restrict__ xbf, const bf16_t* __restrict__ BT,
    const float* __restrict__ biasc,
    float* __restrict__ out_k, bf16_t* __restrict__ vbf, bf16_t* kbf)
{
  __shared__ __align__(16) char smem[32768];
  bf16_t* As = (bf16_t*)smem;             // 128 x 64 bf16 (swizzled granules)
  bf16_t* Bs = (bf16_t*)(smem + 16384);   // 128 x 64 bf16 (swizzled granules)
  float (*Cs)[132] = (float(*)[132])smem; // 16 x 132 fp32 (epilogue reuse)

  const int tid = threadIdx.x, lane = tid & 63, w = tid >> 6;
  const int quad = lane >> 4, l16 = lane & 15;
  const int l = blockIdx.x;
  const int x = l & 7, t = l >> 3;
  const int n0 = (t & 7) * 128;
  const int m0 = ((t >> 3) * 8 + x) * 128;
  const int mb = (w & 1) * 64, nb = (w >> 1) * 64;
  const int swz = l16 & 7;  // row&7 for fragment rows (mb, mt*16 are 0 mod 8)

  const bf16_t* a_base = xbf + (size_t)m0 * 512;
  const bf16_t* b_base = BT + (size_t)n0 * 512;

  f32x4 acc[4][4] = {};

  for (int kk = 0; kk < 512; kk += 64) {
#pragma unroll
    for (int r = 0; r < 4; ++r) {
      int tt = tid + r * 256;            // 0..1023
      int rr = tt >> 3, pg = tt & 7;
      int lg = pg ^ (rr & 7);            // pre-swizzled source granule
      __builtin_amdgcn_global_load_lds((gu32*)(a_base + (size_t)rr * 512 + kk + lg * 8),
                                       (lu32*)&As[tt * 8], 16, 0, 0);
      __builtin_amdgcn_global_load_lds((gu32*)(b_base + (size_t)rr * 512 + kk + lg * 8),
                                       (lu32*)&Bs[tt * 8], 16, 0, 0);
    }
    __syncthreads();
#pragma unroll
    for (int ks = 0; ks < 2; ++ks) {
      bf16x8 af[4], bfr[4];
#pragma unroll
      for (int mt = 0; mt < 4; ++mt)
        af[mt] = *(const bf16x8*)&As[(mb + mt * 16 + l16) * 64 + (((quad + 4 * ks) ^ swz) * 8)];
#pragma unroll
      for (int nt = 0; nt < 4; ++nt)
        bfr[nt] = *(const bf16x8*)&Bs[(nb + nt * 16 + l16) * 64 + (((quad + 4 * ks) ^ swz) * 8)];
#pragma unroll
      for (int mt = 0; mt < 4; ++mt)
#pragma unroll
        for (int nt = 0; nt < 4; ++nt)
          acc[mt][nt] = __builtin_amdgcn_mfma_f32_16x16x32_bf16(af[mt], bfr[nt], acc[mt][nt], 0, 0, 0);
    }
    __syncthreads();
  }

  const int is_k = (n0 < 512);
  const int col4 = (tid * 4) & 127;
  const int row8 = tid >> 4;
  const int col8 = (tid * 8) & 127;
  for (int ci = 0; ci < 8; ++ci) {
    if ((ci < 4) == (mb == 0)) {
      int mt = ci & 3;
#pragma unroll
      for (int nt = 0; nt < 4; ++nt)
#pragma unroll
        for (int r = 0; r < 4; ++r)
          Cs[quad * 4 + r][nb + nt * 16 + l16] = acc[mt][nt][r];
    }
    __syncthreads();
    int rowbase = m0 + ci * 16;
    if (is_k) {
      f32x4 bias4 = *(const f32x4*)&biasc[n0 + col4];
#pragma unroll
      for (int p = 0; p < 2; ++p) {
        int f = p * 1024 + tid * 4;
        int row = f >> 7;
        f32x4 v = *(const f32x4*)&Cs[row][col4] + bias4;
        *(f32x4*)&out_k[(size_t)(rowbase + row) * 512 + n0 + col4] = v;
      }
      if (kbf) {
        f32x4 ba = *(const f32x4*)&biasc[n0 + col8];
        f32x4 bb = *(const f32x4*)&biasc[n0 + col8 + 4];
        f32x4 v0 = *(const f32x4*)&Cs[row8][col8] + ba;
        f32x4 v1 = *(const f32x4*)&Cs[row8][col8 + 4] + bb;
        bf16x8 o;
#pragma unroll
        for (int j = 0; j < 4; ++j) { o[j] = (bf16_t)v0[j]; o[4 + j] = (bf16_t)v1[j]; }
        *(bf16x8*)&kbf[(size_t)(rowbase + row8) * 512 + n0 + col8] = o;
      }
    } else {
      f32x4 ba = *(const f32x4*)&biasc[n0 + col8];
      f32x4 bb = *(const f32x4*)&biasc[n0 + col8 + 4];
      f32x4 v0 = *(const f32x4*)&Cs[row8][col8] + ba;
      f32x4 v1 = *(const f32x4*)&Cs[row8][col8 + 4] + bb;
      bf16x8 o;
#pragma unroll
      for (int j = 0; j < 4; ++j) { o[j] = (bf16_t)v0[j]; o[4 + j] = (bf16_t)v1[j]; }
      *(bf16x8*)&vbf[(size_t)(rowbase + row8) * 512 + (n0 - 512) + col8] = o;
    }
    __syncthreads();
  }
}

// ---------------- ln_q v2: LN(slots) + q GEMV, mlp1-style split ----------------
__global__ __launch_bounds__(256) void ln_q_kernel(
    const float* __restrict__ slots,
    const float* __restrict__ lnsg, const float* __restrict__ lnsb,
    const float* __restrict__ Wq, const float* __restrict__ bq,
    float* __restrict__ q_out)
{
  __shared__ float s[2][512];
  __shared__ float part[4][2][64];
  __shared__ float red1[4], red2[4];
  int tid = threadIdx.x, w = tid >> 6, lane = tid & 63;
  int b = blockIdx.x >> 3, cg = blockIdx.x & 7;

  int r = tid >> 7;
  int off = (tid * 4) & 511;
  float4 v = *(const float4*)&slots[b * 1024 + tid * 4];
  float s1 = v.x + v.y + v.z + v.w;
  float s2 = v.x * v.x + v.y * v.y + v.z * v.z + v.w * v.w;
  s1 = wave_red_sum(s1);
  s2 = wave_red_sum(s2);
  if (lane == 0) { red1[w] = s1; red2[w] = s2; }
  __syncthreads();
  float mean = (red1[r * 2] + red1[r * 2 + 1]) * (1.f / 512.f);
  float var = (red2[r * 2] + red2[r * 2 + 1]) * (1.f / 512.f) - mean * mean;
  float rstd = rsqrtf(var + LN_EPS);
  float4 g4 = *(const float4*)&lnsg[off];
  float4 b4 = *(const float4*)&lnsb[off];
  s[r][off + 0] = (v.x - mean) * rstd * g4.x + b4.x;
  s[r][off + 1] = (v.y - mean) * rstd * g4.y + b4.y;
  s[r][off + 2] = (v.z - mean) * rstd * g4.z + b4.z;
  s[r][off + 3] = (v.w - mean) * rstd * g4.w + b4.w;
  __syncthreads();

  int c = cg * 64 + lane;
  float a0 = 0.f, a1 = 0.f;
  for (int d = w * 128; d < w * 128 + 128; ++d) {
    float wv = Wq[d * 512 + c];
    a0 += s[0][d] * wv;
    a1 += s[1][d] * wv;
  }
  part[w][0][lane] = a0;
  part[w][1][lane] = a1;
  __syncthreads();
  if (tid < 128) {
    int rr = tid >> 6, ll = tid & 63;
    float sum = part[0][rr][ll] + part[1][rr][ll] + part[2][rr][ll] + part[3][rr][ll]
              + bq[cg * 64 + ll];
    q_out[(b * 2 + rr) * 512 + cg * 64 + ll] = sum;
  }
}

// ---------------- attend v3 (fp32 k variant): per-lane-j dots, partial stores ----------------
__global__ __launch_bounds__(256) void attend_fused(
    const float* __restrict__ kf, const bf16_t* __restrict__ vbf,
    const float* __restrict__ qf,
    float* __restrict__ upd_part, float* __restrict__ rs_part,
    float* __restrict__ attn_pre)
{
  __shared__ float qs[2][528];
  __shared__ float p_s[2][64];
  int tid = threadIdx.x, w = tid >> 6, lane = tid & 63;
  int b = blockIdx.x >> 5, chunk = blockIdx.x & 31;
  int j0 = chunk * 64;

  {
    int slot = tid >> 7, pos = (tid & 127) * 4;
    int dq = pos >> 7, dd = pos & 127;
    *(f32x4*)&qs[slot][dq * 132 + dd] = *(const f32x4*)&qf[b * 1024 + slot * 512 + pos];
  }
  __syncthreads();

  int jj = lane & 15;
  int dq = lane >> 4;
  const float* kp = kf + (size_t)(b * 2048 + j0 + w * 16 + jj) * 512 + dq * 128;
  const float* qb0 = &qs[0][dq * 132];
  const float* qb1 = &qs[1][dq * 132];
  float dot0 = 0.f, dot1 = 0.f;
#pragma unroll
  for (int h = 0; h < 4; ++h) {
    f32x4 kr[8];
#pragma unroll
    for (int i = 0; i < 8; ++i) kr[i] = *(const f32x4*)(kp + h * 32 + i * 4);
#pragma unroll
    for (int i = 0; i < 8; ++i) {
      f32x4 qa = *(const f32x4*)(qb0 + h * 32 + i * 4);
      f32x4 qc = *(const f32x4*)(qb1 + h * 32 + i * 4);
#pragma unroll
      for (int t = 0; t < 4; ++t) {
        dot0 += kr[i][t] * qa[t];
        dot1 += kr[i][t] * qc[t];
      }
    }
  }
  dot0 += __shfl_xor(dot0, 16, 64);
  dot0 += __shfl_xor(dot0, 32, 64);
  dot1 += __shfl_xor(dot1, 16, 64);
  dot1 += __shfl_xor(dot1, 32, 64);
  float d0f = dot0 * SCALE_, d1f = dot1 * SCALE_;
  float mx = fmaxf(d0f, d1f);
  float e0 = __expf(d0f - mx), e1 = __expf(d1f - mx);
  float inv = 1.f / (e0 + e1);
  float p0 = e0 * inv, p1 = e1 * inv;
  if (lane < 16) {
    int jj2 = w * 16 + lane;
    p_s[0][jj2] = p0;
    p_s[1][jj2] = p1;
    attn_pre[(b * 2 + 0) * 2048 + j0 + jj2] = p0;
    attn_pre[(b * 2 + 1) * 2048 + j0 + jj2] = p1;
  }
  __syncthreads();

  if (w == 0) {
    float a = p_s[0][lane];
    float c = p_s[1][lane];
    a = wave_red_sum(a);
    c = wave_red_sum(c);
    if (lane == 0) {
      rs_part[(b * 2 + 0) * 32 + chunk] = a;
      rs_part[(b * 2 + 1) * 32 + chunk] = c;
    }
  }

  float u0[8] = {}, u1[8] = {};
  const bf16_t* vp = vbf + (size_t)(b * 2048 + j0 + w * 16) * 512 + lane * 8;
  for (int t = 0; t < 16; ++t) {
    float p0b = p_s[0][w * 16 + t];
    float p1b = p_s[1][w * 16 + t];
    bf16x8 vv = *(const bf16x8*)(vp + (size_t)t * 512);
#pragma unroll
    for (int tt = 0; tt < 8; ++tt) {
      float vfl = (float)vv[tt];
      u0[tt] += p0b * vfl;
      u1[tt] += p1b * vfl;
    }
  }
  float* up0 = upd_part + ((size_t)(chunk * 4 + w) * 64 + b * 2 + 0) * 512 + lane * 8;
  f32x4 w0a = {u0[0], u0[1], u0[2], u0[3]}, w0b = {u0[4], u0[5], u0[6], u0[7]};
  f32x4 w1a = {u1[0], u1[1], u1[2], u1[3]}, w1b = {u1[4], u1[5], u1[6], u1[7]};
  *(f32x4*)(up0) = w0a;
  *(f32x4*)(up0 + 4) = w0b;
  *(f32x4*)(up0 + 512) = w1a;
  *(f32x4*)(up0 + 516) = w1b;
}

// ---------------- attend v3b (bf16 k variant) ----------------
__global__ __launch_bounds__(256) void attend_bf16(
    const bf16_t* __restrict__ kbf, const bf16_t* __restrict__ vbf,
    const float* __restrict__ qf,
    float* __restrict__ upd_part, float* __restrict__ rs_part,
    float* __restrict__ attn_pre)
{
  __shared__ float qs[2][528];
  __shared__ float p_s[2][64];
  int tid = threadIdx.x, w = tid >> 6, lane = tid & 63;
  int b = blockIdx.x >> 5, chunk = blockIdx.x & 31;
  int j0 = chunk * 64;

  {
    int slot = tid >> 7, pos = (tid & 127) * 4;
    int dq = pos >> 7, dd = pos & 127;
    *(f32x4*)&qs[slot][dq * 132 + dd] = *(const f32x4*)&qf[b * 1024 + slot * 512 + pos];
  }
  __syncthreads();

  int jj = lane & 15;
  int dq = lane >> 4;
  const bf16_t* kp = kbf + (size_t)(b * 2048 + j0 + w * 16 + jj) * 512 + dq * 128;
  const float* qb0 = &qs[0][dq * 132];
  const float* qb1 = &qs[1][dq * 132];
  float dot0 = 0.f, dot1 = 0.f;
#pragma unroll
  for (int h = 0; h < 2; ++h) {
    bf16x8 kr[8];
#pragma unroll
    for (int i = 0; i < 8; ++i) kr[i] = *(const bf16x8*)(kp + h * 64 + i * 8);
#pragma unroll
    for (int i = 0; i < 8; ++i) {
      f32x4 qa0 = *(const f32x4*)(qb0 + h * 64 + i * 8);
      f32x4 qa1 = *(const f32x4*)(qb0 + h * 64 + i * 8 + 4);
      f32x4 qc0 = *(const f32x4*)(qb1 + h * 64 + i * 8);
      f32x4 qc1 = *(const f32x4*)(qb1 + h * 64 + i * 8 + 4);
#pragma unroll
      for (int t = 0; t < 4; ++t) {
        float klo = (float)kr[i][t], khi = (float)kr[i][t + 4];
        dot0 += klo * qa0[t] + khi * qa1[t];
        dot1 += klo * qc0[t] + khi * qc1[t];
      }
    }
  }
  dot0 += __shfl_xor(dot0, 16, 64);
  dot0 += __shfl_xor(dot0, 32, 64);
  dot1 += __shfl_xor(dot1, 16, 64);
  dot1 += __shfl_xor(dot1, 32, 64);
  float d0f = dot0 * SCALE_, d1f = dot1 * SCALE_;
  float mx = fmaxf(d0f, d1f);
  float e0 = __expf(d0f - mx), e1 = __expf(d1f - mx);
  float inv = 1.f / (e0 + e1);
  float p0 = e0 * inv, p1 = e1 * inv;
  if (lane < 16) {
    int jj2 = w * 16 + lane;
    p_s[0][jj2] = p0;
    p_s[1][jj2] = p1;
    attn_pre[(b * 2 + 0) * 2048 + j0 + jj2] = p0;
    attn_pre[(b * 2 + 1) * 2048 + j0 + jj2] = p1;
  }
  __syncthreads();

  if (w == 0) {
    float a = p_s[0][lane];
    float c = p_s[1][lane];
    a = wave_red_sum(a);
    c = wave_red_sum(c);
    if (lane == 0) {
      rs_part[(b * 2 + 0) * 32 + chunk] = a;
      rs_part[(b * 2 + 1) * 32 + chunk] = c;
    }
  }

  float u0[8] = {}, u1[8] = {};
  const bf16_t* vp = vbf + (size_t)(b * 2048 + j0 + w * 16) * 512 + lane * 8;
  for (int t = 0; t < 16; ++t) {
    float p0b = p_s[0][w * 16 + t];
    float p1b = p_s[1][w * 16 + t];
    bf16x8 vv = *(const bf16x8*)(vp + (size_t)t * 512);
#pragma unroll
    for (int tt = 0; tt < 8; ++tt) {
      float vfl = (float)vv[tt];
      u0[tt] += p0b * vfl;
      u1[tt] += p1b * vfl;
    }
  }
  float* up0 = upd_part + ((size_t)(chunk * 4 + w) * 64 + b * 2 + 0) * 512 + lane * 8;
  f32x4 w0a = {u0[0], u0[1], u0[2], u0[3]}, w0b = {u0[4], u0[5], u0[6], u0[7]};
  f32x4 w1a = {u1[0], u1[1], u1[2], u1[3]}, w1b = {u1[4], u1[5], u1[6], u1[7]};
  *(f32x4*)(up0) = w0a;
  *(f32x4*)(up0 + 4) = w0b;
  *(f32x4*)(up0 + 512) = w1a;
  *(f32x4*)(up0 + 516) = w1b;
}

// ---------------- reduce_upd: sum 128 partials -> upd, rowsum ----------------
__global__ __launch_bounds__(512) void reduce_upd(
    const float* __restrict__ upd_part, const float* __restrict__ rs_part,
    float* __restrict__ upd, float* __restrict__ rowsum)
{
  int r = blockIdx.x, tid = threadIdx.x;
  const float* p = upd_part + (size_t)r * 512 + tid;
  float acc = 0.f;
#pragma unroll 8
  for (int i = 0; i < 128; ++i) acc += p[(size_t)i * 32768];
  upd[r * 512 + tid] = acc;
  if (tid < 64) {
    float v = (tid < 32) ? rs_part[r * 32 + tid] : 0.f;
    v = wave_red_sum(v);
    if (tid == 0) rowsum[r] = v;
  }
}

// ---------------- gates: gx = u@wihT + bih, gh = h@whhT + bhh ----------------
__global__ __launch_bounds__(256) void gates_kernel(
    const float* __restrict__ slots, const float* __restrict__ upd,
    const float* __restrict__ rowsum,
    const float* __restrict__ wihT, const float* __restrict__ whhT,
    const float* __restrict__ bih, const float* __restrict__ bhh,
    float* __restrict__ gx, float* __restrict__ gh)
{
  __shared__ float in_s[2][512];
  __shared__ float part[4][2][256];
  int tid = threadIdx.x, w = tid >> 6, lane = tid & 63;
  int rg = blockIdx.x / 12, cc = blockIdx.x % 12;
  int is_gh = (cc >= 6);
  int ccl = is_gh ? cc - 6 : cc;
  {
    int rr = tid >> 7, pos = (tid & 127) * 4;
    int row = rg * 2 + rr;
    const float* src = (is_gh ? slots : upd) + row * 512;
    f32x4 v = *(const f32x4*)&src[pos];
    if (!is_gh) v *= 1.f / (rowsum[row] + EPS_);
    *(f32x4*)&in_s[rr][pos] = v;
  }
  __syncthreads();
  int c0 = ccl * 256 + lane * 4;
  const float* __restrict__ W = is_gh ? whhT : wihT;
  f32x4 acc0 = {0.f, 0.f, 0.f, 0.f}, acc1 = acc0;
  for (int d = w * 128; d < w * 128 + 128; ++d) {
    f32x4 w4 = *(const f32x4*)&W[d * 1536 + c0];
    acc0 += in_s[0][d] * w4;
    acc1 += in_s[1][d] * w4;
  }
  *(f32x4*)&part[w][0][lane * 4] = acc0;
  *(f32x4*)&part[w][1][lane * 4] = acc1;
  __syncthreads();
  if (tid < 128) {
    int r = tid >> 6, ll = tid & 63;
    int cf = ccl * 256 + ll * 4;
    f32x4 s = *(const f32x4*)&part[0][r][ll * 4];
    s += *(const f32x4*)&part[1][r][ll * 4];
    s += *(const f32x4*)&part[2][r][ll * 4];
    s += *(const f32x4*)&part[3][r][ll * 4];
    s += *(const f32x4*)&(is_gh ? bhh : bih)[cf];
    *(f32x4*)&(is_gh ? gh : gx)[(rg * 2 + r) * 1536 + cf] = s;
  }
}

// ---------------- GRU elementwise + LN -> hnew, hln ----------------
__global__ __launch_bounds__(512) void gru_ln_kernel(
    const float* __restrict__ gx, const float* __restrict__ gh,
    const float* __restrict__ slots,
    const float* __restrict__ lnf_g, const float* __restrict__ lnf_b,
    float* __restrict__ hnew, float* __restrict__ hln)
{
  __shared__ float red1[8], red2[8];
  int tid = threadIdx.x, row = blockIdx.x;
  float gxr = gx[row * 1536 + tid], gxz = gx[row * 1536 + 512 + tid], gxn = gx[row * 1536 + 1024 + tid];
  float ghr = gh[row * 1536 + tid], ghz = gh[row * 1536 + 512 + tid], ghn = gh[row * 1536 + 1024 + tid];
  float h = slots[row * 512 + tid];
  float r_ = 1.f / (1.f + __expf(-(gxr + ghr)));
  float z_ = 1.f / (1.f + __expf(-(gxz + ghz)));
  float n_ = tanhf(gxn + r_ * ghn);
  float hn = (1.f - z_) * n_ + z_ * h;
  hnew[row * 512 + tid] = hn;
  float s1 = wave_red_sum(hn), s2 = wave_red_sum(hn * hn);
  int w = tid >> 6, lane = tid & 63;
  if (lane == 0) { red1[w] = s1; red2[w] = s2; }
  __syncthreads();
  s1 = 0.f; s2 = 0.f;
#pragma unroll
  for (int i = 0; i < 8; ++i) { s1 += red1[i]; s2 += red2[i]; }
  float mean = s1 * (1.f / 512.f);
  float var = s2 * (1.f / 512.f) - mean * mean;
  float rstd = rsqrtf(var + LN_EPS);
  hln[row * 512 + tid] = (hn - mean) * rstd * lnf_g[tid] + lnf_b[tid];
}

// ---------------- mlp1: act = relu(hln @ W1 + b1) ----------------
__global__ __launch_bounds__(256) void mlp1_kernel(
    const float* __restrict__ hln, const float* __restrict__ W1,
    const float* __restrict__ b1, float* __restrict__ act)
{
  __shared__ float in_s[2][512];
  __shared__ float part[4][2][64];
  int tid = threadIdx.x, w = tid >> 6, lane = tid & 63;
  int rg = blockIdx.x >> 3, cc = blockIdx.x & 7;
  {
    int rr = tid >> 7, pos = (tid & 127) * 4;
    *(f32x4*)&in_s[rr][pos] = *(const f32x4*)&hln[(rg * 2 + rr) * 512 + pos];
  }
  __syncthreads();
  int c = cc * 64 + lane;
  float a0 = 0.f, a1 = 0.f;
  for (int d = w * 128; d < w * 128 + 128; ++d) {
    float wv = W1[d * 512 + c];
    a0 += in_s[0][d] * wv;
    a1 += in_s[1][d] * wv;
  }
  part[w][0][lane] = a0;
  part[w][1][lane] = a1;
  __syncthreads();
  if (tid < 128) {
    int r = tid >> 6, ll = tid & 63;
    float s = part[0][r][ll] + part[1][r][ll] + part[2][r][ll] + part[3][r][ll]
            + b1[cc * 64 + ll];
    act[(rg * 2 + r) * 512 + cc * 64 + ll] = fmaxf(s, 0.f);
  }
}

// ---------------- mlp2: slots = hnew + act @ W2 + b2 ----------------
__global__ __launch_bounds__(256) void mlp2_kernel(
    const float* __restrict__ act, const float* __restrict__ W2,
    const float* __restrict__ b2, const float* __restrict__ hnew,
    float* __restrict__ slots)
{
  __shared__ float in_s[2][512];
  __shared__ float part[4][2][64];
  int tid = threadIdx.x, w = tid >> 6, lane = tid & 63;
  int rg = blockIdx.x >> 3, cc = blockIdx.x & 7;
  {
    int rr = tid >> 7, pos = (tid & 127) * 4;
    *(f32x4*)&in_s[rr][pos] = *(const f32x4*)&act[(rg * 2 + rr) * 512 + pos];
  }
  __syncthreads();
  int c = cc * 64 + lane;
  float a0 = 0.f, a1 = 0.f;
  for (int d = w * 128; d < w * 128 + 128; ++d) {
    float wv = W2[d * 512 + c];
    a0 += in_s[0][d] * wv;
    a1 += in_s[1][d] * wv;
  }
  part[w][0][lane] = a0;
  part[w][1][lane] = a1;
  __syncthreads();
  if (tid < 128) {
    int r = tid >> 6, ll = tid & 63;
    int row = rg * 2 + r, c2 = cc * 64 + ll;
    float s = part[0][r][ll] + part[1][r][ll] + part[2][r][ll] + part[3][r][ll] + b2[c2];
    slots[row * 512 + c2] = hnew[row * 512 + c2] + s;
  }
}

// ---------------- attn normalize in place ----------------
__global__ __launch_bounds__(256) void norm_attn(
    const float* __restrict__ rowsum, float* __restrict__ attn)
{
  int idx = blockIdx.x * 256 + threadIdx.x;  // < 131072
  int row = idx >> 11;
  attn[idx] = attn[idx] / (rowsum[row] + EPS_);
}

extern "C" void kernel_launch(void* const* d_in, const int* in_sizes, int n_in,
                              void* d_out, int out_size, void* d_ws, size_t ws_size,
                              hipStream_t stream)
{
  const float* inputs     = (const float*)d_in[0];
  const float* slots_init = (const float*)d_in[1];
  const float* Wq   = (const float*)d_in[2];
  const float* bq   = (const float*)d_in[3];
  const float* Wk   = (const float*)d_in[4];
  const float* bk   = (const float*)d_in[5];
  const float* Wv   = (const float*)d_in[6];
  const float* bv   = (const float*)d_in[7];
  const float* ln_in_g = (const float*)d_in[8];
  const float* ln_in_b = (const float*)d_in[9];
  const float* ln_s_g  = (const float*)d_in[10];
  const float* ln_s_b  = (const float*)d_in[11];
  const float* ln_f_g  = (const float*)d_in[12];
  const float* ln_f_b  = (const float*)d_in[13];
  const float* wih  = (const float*)d_in[14];
  const float* whh  = (const float*)d_in[15];
  const float* bih  = (const float*)d_in[16];
  const float* bhh  = (const float*)d_in[17];
  const float* W1   = (const float*)d_in[18];
  const float* b1   = (const float*)d_in[19];
  const float* W2   = (const float*)d_in[20];
  const float* b2   = (const float*)d_in[21];

  float* out   = (float*)d_out;
  float* slots = out;                 // [32,2,512] working + final output
  float* q_out = out + 32768;         // [32,2,512]
  float* k_out = out + 65536;         // [32,2048,512] fp32 k (required output)
  float* attnp = out + 33619968;      // [32,2,2048] attn (normalized at end)

  char* ws = (char*)d_ws;
  bf16_t* xbf   = (bf16_t*)(ws);                    // 67,108,864 LN(inputs) bf16 (dead after gemm)
  float*  upd_part = (float*)(ws);                  // 16,777,216 (alias xbf; live in iters)
  float*  rs_part  = (float*)(ws + 16777216);       //      8,192 (alias xbf)
  bf16_t* vbf   = (bf16_t*)(ws + 67108864);         // 67,108,864
  bf16_t* BT    = (bf16_t*)(ws + 134217728);        //  1,048,576 (dead after gemm)
  float*  gx    = (float*)(ws + 134217728);         //    393,216 (alias)
  float*  gh    = (float*)(ws + 134610944);         //    393,216
  float*  hnew  = (float*)(ws + 135004160);         //    131,072
  float*  hln   = (float*)(ws + 135135232);         //    131,072
  float*  wihT  = (float*)(ws + 135266304);         //  3,145,728
  float*  whhT  = (float*)(ws + 138412032);         //  3,145,728
  float*  biasc = (float*)(ws + 141557760);         //      4,096
  float*  act   = (float*)(ws + 141561856);         //    131,072
  float*  upd   = (float*)(ws + 142086144);         //    131,072
  float*  rowsum= (float*)(ws + 142217216);         //        256  -> end 142,217,472

  // optional bf16 k for attend, gated on workspace size
  const size_t kbf_off = 142217472ull;               // 16B aligned
  const bool big_ws = ws_size >= kbf_off + 67108864ull;
  bf16_t* kbf = big_ws ? (bf16_t*)(ws + kbf_off) : (bf16_t*)nullptr;

  transpose_prep<<<dim3(16, 48, 4), 256, 0, stream>>>(Wk, Wv, wih, whh, BT, wihT, whhT);
  small_prep<<<132, 256, 0, stream>>>(bk, bv, slots_init, biasc, slots);
  ln_apply<<<16384, 256, 0, stream>>>(inputs, ln_in_g, ln_in_b, xbf);
  gemm_kv<<<4096, 256, 0, stream>>>(xbf, BT, biasc, k_out, vbf, kbf);
  for (int it = 0; it < 3; ++it) {
    ln_q_kernel<<<256, 256, 0, stream>>>(slots, ln_s_g, ln_s_b, Wq, bq, q_out);
    if (big_ws)
      attend_bf16<<<1024, 256, 0, stream>>>(kbf, vbf, q_out, upd_part, rs_part, attnp);
    else
      attend_fused<<<1024, 256, 0, stream>>>(k_out, vbf, q_out, upd_part, rs_part, attnp);
    reduce_upd<<<64, 512, 0, stream>>>(upd_part, rs_part, upd, rowsum);
    gates_kernel<<<384, 256, 0, stream>>>(slots, upd, rowsum, wihT, whhT, bih, bhh, gx, gh);
    gru_ln_kernel<<<64, 512, 0, stream>>>(gx, gh, slots, ln_f_g, ln_f_b, hnew, hln);
    mlp1_kernel<<<256, 256, 0, stream>>>(hln, W1, b1, act);
    mlp2_kernel<<<256, 256, 0, stream>>>(act, W2, b2, hnew, slots);
  }
  norm_attn<<<512, 256, 0, stream>>>(rowsum, attnp);
}

// Round 7
// 617.587 us; speedup vs baseline: 1.5790x; 1.0291x over previous
//
#include <hip/hip_runtime.h>
#include <stdint.h>

typedef __bf16 bf16_t;
typedef bf16_t bf16x8 __attribute__((ext_vector_type(8)));
typedef float f32x4 __attribute__((ext_vector_type(4)));

typedef unsigned int u32;
typedef __attribute__((address_space(1))) const u32 gu32;
typedef __attribute__((address_space(3))) u32 lu32;

#define LN_EPS 1e-5f
#define EPS_ 1e-8f
#define SCALE_ 0.04419417382415922f  // 512^-0.5

__device__ __forceinline__ float wave_red_sum(float v) {
#pragma unroll
  for (int off = 32; off > 0; off >>= 1) v += __shfl_xor(v, off, 64);
  return v;
}

// ---------------- prep: LDS-tiled transposes (coalesced both sides) ----------------
__global__ __launch_bounds__(256) void transpose_prep(
    const float* __restrict__ Wk, const float* __restrict__ Wv,
    const float* __restrict__ wih, const float* __restrict__ whh,
    bf16_t* __restrict__ BT, float* __restrict__ wihT, float* __restrict__ whhT)
{
  int z = blockIdx.z;
  if (z < 2 && blockIdx.y >= 16) return;
  const float* src = (z == 0) ? Wk : (z == 1) ? Wv : (z == 2) ? wih : whh;
  __shared__ float tile[32][33];
  int tx = threadIdx.x & 31, ty = threadIdx.x >> 5;  // 32 x 8
  int row0 = blockIdx.y * 32, col0 = blockIdx.x * 32;
#pragma unroll
  for (int i = 0; i < 4; ++i)
    tile[ty + 8 * i][tx] = src[(size_t)(row0 + ty + 8 * i) * 512 + col0 + tx];
  __syncthreads();
  if (z < 2) {
#pragma unroll
    for (int i = 0; i < 4; ++i)
      BT[(size_t)(z * 512 + col0 + ty + 8 * i) * 512 + row0 + tx] =
          (bf16_t)tile[tx][ty + 8 * i];
  } else {
    float* dst = (z == 2) ? wihT : whhT;
#pragma unroll
    for (int i = 0; i < 4; ++i)
      dst[(size_t)(col0 + ty + 8 * i) * 1536 + row0 + tx] = tile[tx][ty + 8 * i];
  }
}

// ---------------- small prep: biasc pack + slots init (into d_out) ----------------
__global__ __launch_bounds__(256) void small_prep(
    const float* __restrict__ bk, const float* __restrict__ bv,
    const float* __restrict__ slots_init,
    float* __restrict__ biasc, float* __restrict__ slots)
{
  int idx = blockIdx.x * 256 + threadIdx.x;  // < 33792
  if (idx < 1024) {
    biasc[idx] = (idx < 512) ? bk[idx] : bv[idx - 512];
  } else {
    int i = idx - 1024;  // < 32768
    slots[i] = slots_init[i];
  }
}

// ---------------- LN(inputs) -> bf16, one wave per row ----------------
__global__ __launch_bounds__(256) void ln_apply(
    const float* __restrict__ in, const float* __restrict__ lng,
    const float* __restrict__ lnb, bf16_t* __restrict__ xbf)
{
  int w = threadIdx.x >> 6, lane = threadIdx.x & 63;
  size_t row = (size_t)blockIdx.x * 4 + w;
  const float4* rp = (const float4*)(in + row * 512);
  float4 a = rp[lane * 2], c = rp[lane * 2 + 1];
  float s1 = a.x + a.y + a.z + a.w + c.x + c.y + c.z + c.w;
  float s2 = a.x * a.x + a.y * a.y + a.z * a.z + a.w * a.w +
             c.x * c.x + c.y * c.y + c.z * c.z + c.w * c.w;
  s1 = wave_red_sum(s1);
  s2 = wave_red_sum(s2);
  float mean = s1 * (1.f / 512.f);
  float var = s2 * (1.f / 512.f) - mean * mean;
  float rs = rsqrtf(var + LN_EPS);
  float4 g0 = *(const float4*)&lng[lane * 8];
  float4 g1 = *(const float4*)&lng[lane * 8 + 4];
  float4 b0 = *(const float4*)&lnb[lane * 8];
  float4 b1 = *(const float4*)&lnb[lane * 8 + 4];
  bf16x8 o;
  o[0] = (bf16_t)((a.x - mean) * rs * g0.x + b0.x);
  o[1] = (bf16_t)((a.y - mean) * rs * g0.y + b0.y);
  o[2] = (bf16_t)((a.z - mean) * rs * g0.z + b0.z);
  o[3] = (bf16_t)((a.w - mean) * rs * g0.w + b0.w);
  o[4] = (bf16_t)((c.x - mean) * rs * g1.x + b1.x);
  o[5] = (bf16_t)((c.y - mean) * rs * g1.y + b1.y);
  o[6] = (bf16_t)((c.z - mean) * rs * g1.z + b1.z);
  o[7] = (bf16_t)((c.w - mean) * rs * g1.w + b1.w);
  *(bf16x8*)&xbf[row * 512 + lane * 8] = o;
}

// ---------------- bf16 MFMA GEMM: 2-phase pipelined dbuf + direct-register epilogue ----------------
// BK=32, 2 LDS buffers (32 KB). Loads for tile t+1 issue BEFORE compute of tile t;
// the end-of-step __syncthreads drains them only after ~400cy of ds_read+MFMA cover.
// Epilogue: C/D layout col=lane&15,row=quad*4+reg -> store straight from acc, 0 barriers.
__global__ __launch_bounds__(256) void gemm_kv(
    const bf16_t* __restrict__ xbf, const bf16_t* __restrict__ BT,
    const float* __restrict__ biasc,
    float* __restrict__ out_k, bf16_t* __restrict__ vbf, bf16_t* kbf)
{
  __shared__ __align__(16) char smem[32768];

  const int tid = threadIdx.x, lane = tid & 63, w = tid >> 6;
  const int quad = lane >> 4, l16 = lane & 15;
  const int l = blockIdx.x;
  const int x = l & 7, t0 = l >> 3;
  const int n0 = (t0 & 7) * 128;
  const int m0 = ((t0 >> 3) * 8 + x) * 128;
  const int mb = (w & 1) * 64, nb = (w >> 1) * 64;
  const int swz = (l16 >> 1) & 3;

  const bf16_t* a_base = xbf + (size_t)m0 * 512;
  const bf16_t* b_base = BT + (size_t)n0 * 512;

  f32x4 acc[4][4] = {};

  auto stage = [&](int buf, int kk) {
    bf16_t* As = (bf16_t*)(smem + buf * 16384);
    bf16_t* Bs = (bf16_t*)(smem + buf * 16384 + 8192);
#pragma unroll
    for (int r = 0; r < 2; ++r) {
      int tt = tid + r * 256;            // 0..511
      int rr = tt >> 2, pg = tt & 3;
      int lg = pg ^ ((rr >> 1) & 3);     // pre-swizzled source granule
      __builtin_amdgcn_global_load_lds((gu32*)(a_base + (size_t)rr * 512 + kk + lg * 8),
                                       (lu32*)&As[tt * 8], 16, 0, 0);
      __builtin_amdgcn_global_load_lds((gu32*)(b_base + (size_t)rr * 512 + kk + lg * 8),
                                       (lu32*)&Bs[tt * 8], 16, 0, 0);
    }
  };

  auto compute = [&](int buf) {
    const bf16_t* As = (const bf16_t*)(smem + buf * 16384);
    const bf16_t* Bs = (const bf16_t*)(smem + buf * 16384 + 8192);
    bf16x8 af[4], bfr[4];
#pragma unroll
    for (int mt = 0; mt < 4; ++mt)
      af[mt] = *(const bf16x8*)&As[(mb + mt * 16 + l16) * 32 + ((quad ^ swz) * 8)];
#pragma unroll
    for (int nt = 0; nt < 4; ++nt)
      bfr[nt] = *(const bf16x8*)&Bs[(nb + nt * 16 + l16) * 32 + ((quad ^ swz) * 8)];
#pragma unroll
    for (int mt = 0; mt < 4; ++mt)
#pragma unroll
      for (int nt = 0; nt < 4; ++nt)
        acc[mt][nt] = __builtin_amdgcn_mfma_f32_16x16x32_bf16(af[mt], bfr[nt], acc[mt][nt], 0, 0, 0);
  };

  stage(0, 0);
  __syncthreads();
#pragma unroll
  for (int t = 0; t < 16; ++t) {
    if (t < 15) stage((t + 1) & 1, (t + 1) * 32);
    compute(t & 1);
    if (t < 15) __syncthreads();
  }

  // ---- direct-register epilogue (no LDS, no barriers) ----
  const int is_k = (n0 < 512);
  const int rbase = m0 + mb + quad * 4;
  if (is_k) {
#pragma unroll
    for (int nt = 0; nt < 4; ++nt) {
      int col = n0 + nb + nt * 16 + l16;
      float bias = biasc[col];
#pragma unroll
      for (int mt = 0; mt < 4; ++mt) {
        int row = rbase + mt * 16;
#pragma unroll
        for (int r = 0; r < 4; ++r) {
          float v = acc[mt][nt][r] + bias;
          out_k[(size_t)(row + r) * 512 + col] = v;
        }
      }
    }
    if (kbf) {
#pragma unroll
      for (int nt = 0; nt < 4; ++nt) {
        int col = n0 + nb + nt * 16 + l16;
        float bias = biasc[col];
#pragma unroll
        for (int mt = 0; mt < 4; ++mt) {
          int row = rbase + mt * 16;
#pragma unroll
          for (int r = 0; r < 4; ++r)
            kbf[(size_t)(row + r) * 512 + col] = (bf16_t)(acc[mt][nt][r] + bias);
        }
      }
    }
  } else {
#pragma unroll
    for (int nt = 0; nt < 4; ++nt) {
      int colg = n0 + nb + nt * 16 + l16;
      float bias = biasc[colg];
      int col = colg - 512;
#pragma unroll
      for (int mt = 0; mt < 4; ++mt) {
        int row = rbase + mt * 16;
#pragma unroll
        for (int r = 0; r < 4; ++r)
          vbf[(size_t)(row + r) * 512 + col] = (bf16_t)(acc[mt][nt][r] + bias);
      }
    }
  }
}

// ---------------- ln_q v2: LN(slots) + q GEMV, mlp1-style split ----------------
__global__ __launch_bounds__(256) void ln_q_kernel(
    const float* __restrict__ slots,
    const float* __restrict__ lnsg, const float* __restrict__ lnsb,
    const float* __restrict__ Wq, const float* __restrict__ bq,
    float* __restrict__ q_out)
{
  __shared__ float s[2][512];
  __shared__ float part[4][2][64];
  __shared__ float red1[4], red2[4];
  int tid = threadIdx.x, w = tid >> 6, lane = tid & 63;
  int b = blockIdx.x >> 3, cg = blockIdx.x & 7;

  int r = tid >> 7;
  int off = (tid * 4) & 511;
  float4 v = *(const float4*)&slots[b * 1024 + tid * 4];
  float s1 = v.x + v.y + v.z + v.w;
  float s2 = v.x * v.x + v.y * v.y + v.z * v.z + v.w * v.w;
  s1 = wave_red_sum(s1);
  s2 = wave_red_sum(s2);
  if (lane == 0) { red1[w] = s1; red2[w] = s2; }
  __syncthreads();
  float mean = (red1[r * 2] + red1[r * 2 + 1]) * (1.f / 512.f);
  float var = (red2[r * 2] + red2[r * 2 + 1]) * (1.f / 512.f) - mean * mean;
  float rstd = rsqrtf(var + LN_EPS);
  float4 g4 = *(const float4*)&lnsg[off];
  float4 b4 = *(const float4*)&lnsb[off];
  s[r][off + 0] = (v.x - mean) * rstd * g4.x + b4.x;
  s[r][off + 1] = (v.y - mean) * rstd * g4.y + b4.y;
  s[r][off + 2] = (v.z - mean) * rstd * g4.z + b4.z;
  s[r][off + 3] = (v.w - mean) * rstd * g4.w + b4.w;
  __syncthreads();

  int c = cg * 64 + lane;
  float a0 = 0.f, a1 = 0.f;
  for (int d = w * 128; d < w * 128 + 128; ++d) {
    float wv = Wq[d * 512 + c];
    a0 += s[0][d] * wv;
    a1 += s[1][d] * wv;
  }
  part[w][0][lane] = a0;
  part[w][1][lane] = a1;
  __syncthreads();
  if (tid < 128) {
    int rr = tid >> 6, ll = tid & 63;
    float sum = part[0][rr][ll] + part[1][rr][ll] + part[2][rr][ll] + part[3][rr][ll]
              + bq[cg * 64 + ll];
    q_out[(b * 2 + rr) * 512 + cg * 64 + ll] = sum;
  }
}

// ---------------- attend v3 (fp32 k variant): per-lane-j dots, partial stores ----------------
__global__ __launch_bounds__(256) void attend_fused(
    const float* __restrict__ kf, const bf16_t* __restrict__ vbf,
    const float* __restrict__ qf,
    float* __restrict__ upd_part, float* __restrict__ rs_part,
    float* __restrict__ attn_pre)
{
  __shared__ float qs[2][528];
  __shared__ float p_s[2][64];
  int tid = threadIdx.x, w = tid >> 6, lane = tid & 63;
  int b = blockIdx.x >> 5, chunk = blockIdx.x & 31;
  int j0 = chunk * 64;

  {
    int slot = tid >> 7, pos = (tid & 127) * 4;
    int dq = pos >> 7, dd = pos & 127;
    *(f32x4*)&qs[slot][dq * 132 + dd] = *(const f32x4*)&qf[b * 1024 + slot * 512 + pos];
  }
  __syncthreads();

  int jj = lane & 15;
  int dq = lane >> 4;
  const float* kp = kf + (size_t)(b * 2048 + j0 + w * 16 + jj) * 512 + dq * 128;
  const float* qb0 = &qs[0][dq * 132];
  const float* qb1 = &qs[1][dq * 132];
  float dot0 = 0.f, dot1 = 0.f;
#pragma unroll
  for (int h = 0; h < 4; ++h) {
    f32x4 kr[8];
#pragma unroll
    for (int i = 0; i < 8; ++i) kr[i] = *(const f32x4*)(kp + h * 32 + i * 4);
#pragma unroll
    for (int i = 0; i < 8; ++i) {
      f32x4 qa = *(const f32x4*)(qb0 + h * 32 + i * 4);
      f32x4 qc = *(const f32x4*)(qb1 + h * 32 + i * 4);
#pragma unroll
      for (int t = 0; t < 4; ++t) {
        dot0 += kr[i][t] * qa[t];
        dot1 += kr[i][t] * qc[t];
      }
    }
  }
  dot0 += __shfl_xor(dot0, 16, 64);
  dot0 += __shfl_xor(dot0, 32, 64);
  dot1 += __shfl_xor(dot1, 16, 64);
  dot1 += __shfl_xor(dot1, 32, 64);
  float d0f = dot0 * SCALE_, d1f = dot1 * SCALE_;
  float mx = fmaxf(d0f, d1f);
  float e0 = __expf(d0f - mx), e1 = __expf(d1f - mx);
  float inv = 1.f / (e0 + e1);
  float p0 = e0 * inv, p1 = e1 * inv;
  if (lane < 16) {
    int jj2 = w * 16 + lane;
    p_s[0][jj2] = p0;
    p_s[1][jj2] = p1;
    attn_pre[(b * 2 + 0) * 2048 + j0 + jj2] = p0;
    attn_pre[(b * 2 + 1) * 2048 + j0 + jj2] = p1;
  }
  __syncthreads();

  if (w == 0) {
    float a = p_s[0][lane];
    float c = p_s[1][lane];
    a = wave_red_sum(a);
    c = wave_red_sum(c);
    if (lane == 0) {
      rs_part[(b * 2 + 0) * 32 + chunk] = a;
      rs_part[(b * 2 + 1) * 32 + chunk] = c;
    }
  }

  float u0[8] = {}, u1[8] = {};
  const bf16_t* vp = vbf + (size_t)(b * 2048 + j0 + w * 16) * 512 + lane * 8;
  for (int t = 0; t < 16; ++t) {
    float p0b = p_s[0][w * 16 + t];
    float p1b = p_s[1][w * 16 + t];
    bf16x8 vv = *(const bf16x8*)(vp + (size_t)t * 512);
#pragma unroll
    for (int tt = 0; tt < 8; ++tt) {
      float vfl = (float)vv[tt];
      u0[tt] += p0b * vfl;
      u1[tt] += p1b * vfl;
    }
  }
  float* up0 = upd_part + ((size_t)(chunk * 4 + w) * 64 + b * 2 + 0) * 512 + lane * 8;
  f32x4 w0a = {u0[0], u0[1], u0[2], u0[3]}, w0b = {u0[4], u0[5], u0[6], u0[7]};
  f32x4 w1a = {u1[0], u1[1], u1[2], u1[3]}, w1b = {u1[4], u1[5], u1[6], u1[7]};
  *(f32x4*)(up0) = w0a;
  *(f32x4*)(up0 + 4) = w0b;
  *(f32x4*)(up0 + 512) = w1a;
  *(f32x4*)(up0 + 516) = w1b;
}

// ---------------- attend v3b (bf16 k variant) ----------------
__global__ __launch_bounds__(256) void attend_bf16(
    const bf16_t* __restrict__ kbf, const bf16_t* __restrict__ vbf,
    const float* __restrict__ qf,
    float* __restrict__ upd_part, float* __restrict__ rs_part,
    float* __restrict__ attn_pre)
{
  __shared__ float qs[2][528];
  __shared__ float p_s[2][64];
  int tid = threadIdx.x, w = tid >> 6, lane = tid & 63;
  int b = blockIdx.x >> 5, chunk = blockIdx.x & 31;
  int j0 = chunk * 64;

  {
    int slot = tid >> 7, pos = (tid & 127) * 4;
    int dq = pos >> 7, dd = pos & 127;
    *(f32x4*)&qs[slot][dq * 132 + dd] = *(const f32x4*)&qf[b * 1024 + slot * 512 + pos];
  }
  __syncthreads();

  int jj = lane & 15;
  int dq = lane >> 4;
  const bf16_t* kp = kbf + (size_t)(b * 2048 + j0 + w * 16 + jj) * 512 + dq * 128;
  const float* qb0 = &qs[0][dq * 132];
  const float* qb1 = &qs[1][dq * 132];
  float dot0 = 0.f, dot1 = 0.f;
#pragma unroll
  for (int h = 0; h < 2; ++h) {
    bf16x8 kr[8];
#pragma unroll
    for (int i = 0; i < 8; ++i) kr[i] = *(const bf16x8*)(kp + h * 64 + i * 8);
#pragma unroll
    for (int i = 0; i < 8; ++i) {
      f32x4 qa0 = *(const f32x4*)(qb0 + h * 64 + i * 8);
      f32x4 qa1 = *(const f32x4*)(qb0 + h * 64 + i * 8 + 4);
      f32x4 qc0 = *(const f32x4*)(qb1 + h * 64 + i * 8);
      f32x4 qc1 = *(const f32x4*)(qb1 + h * 64 + i * 8 + 4);
#pragma unroll
      for (int t = 0; t < 4; ++t) {
        float klo = (float)kr[i][t], khi = (float)kr[i][t + 4];
        dot0 += klo * qa0[t] + khi * qa1[t];
        dot1 += klo * qc0[t] + khi * qc1[t];
      }
    }
  }
  dot0 += __shfl_xor(dot0, 16, 64);
  dot0 += __shfl_xor(dot0, 32, 64);
  dot1 += __shfl_xor(dot1, 16, 64);
  dot1 += __shfl_xor(dot1, 32, 64);
  float d0f = dot0 * SCALE_, d1f = dot1 * SCALE_;
  float mx = fmaxf(d0f, d1f);
  float e0 = __expf(d0f - mx), e1 = __expf(d1f - mx);
  float inv = 1.f / (e0 + e1);
  float p0 = e0 * inv, p1 = e1 * inv;
  if (lane < 16) {
    int jj2 = w * 16 + lane;
    p_s[0][jj2] = p0;
    p_s[1][jj2] = p1;
    attn_pre[(b * 2 + 0) * 2048 + j0 + jj2] = p0;
    attn_pre[(b * 2 + 1) * 2048 + j0 + jj2] = p1;
  }
  __syncthreads();

  if (w == 0) {
    float a = p_s[0][lane];
    float c = p_s[1][lane];
    a = wave_red_sum(a);
    c = wave_red_sum(c);
    if (lane == 0) {
      rs_part[(b * 2 + 0) * 32 + chunk] = a;
      rs_part[(b * 2 + 1) * 32 + chunk] = c;
    }
  }

  float u0[8] = {}, u1[8] = {};
  const bf16_t* vp = vbf + (size_t)(b * 2048 + j0 + w * 16) * 512 + lane * 8;
  for (int t = 0; t < 16; ++t) {
    float p0b = p_s[0][w * 16 + t];
    float p1b = p_s[1][w * 16 + t];
    bf16x8 vv = *(const bf16x8*)(vp + (size_t)t * 512);
#pragma unroll
    for (int tt = 0; tt < 8; ++tt) {
      float vfl = (float)vv[tt];
      u0[tt] += p0b * vfl;
      u1[tt] += p1b * vfl;
    }
  }
  float* up0 = upd_part + ((size_t)(chunk * 4 + w) * 64 + b * 2 + 0) * 512 + lane * 8;
  f32x4 w0a = {u0[0], u0[1], u0[2], u0[3]}, w0b = {u0[4], u0[5], u0[6], u0[7]};
  f32x4 w1a = {u1[0], u1[1], u1[2], u1[3]}, w1b = {u1[4], u1[5], u1[6], u1[7]};
  *(f32x4*)(up0) = w0a;
  *(f32x4*)(up0 + 4) = w0b;
  *(f32x4*)(up0 + 512) = w1a;
  *(f32x4*)(up0 + 516) = w1b;
}

// ---------------- reduce_upd: sum 128 partials -> upd, rowsum ----------------
__global__ __launch_bounds__(512) void reduce_upd(
    const float* __restrict__ upd_part, const float* __restrict__ rs_part,
    float* __restrict__ upd, float* __restrict__ rowsum)
{
  int r = blockIdx.x, tid = threadIdx.x;
  const float* p = upd_part + (size_t)r * 512 + tid;
  float acc = 0.f;
#pragma unroll 8
  for (int i = 0; i < 128; ++i) acc += p[(size_t)i * 32768];
  upd[r * 512 + tid] = acc;
  if (tid < 64) {
    float v = (tid < 32) ? rs_part[r * 32 + tid] : 0.f;
    v = wave_red_sum(v);
    if (tid == 0) rowsum[r] = v;
  }
}

// ---------------- gates: gx = u@wihT + bih, gh = h@whhT + bhh ----------------
__global__ __launch_bounds__(256) void gates_kernel(
    const float* __restrict__ slots, const float* __restrict__ upd,
    const float* __restrict__ rowsum,
    const float* __restrict__ wihT, const float* __restrict__ whhT,
    const float* __restrict__ bih, const float* __restrict__ bhh,
    float* __restrict__ gx, float* __restrict__ gh)
{
  __shared__ float in_s[2][512];
  __shared__ float part[4][2][256];
  int tid = threadIdx.x, w = tid >> 6, lane = tid & 63;
  int rg = blockIdx.x / 12, cc = blockIdx.x % 12;
  int is_gh = (cc >= 6);
  int ccl = is_gh ? cc - 6 : cc;
  {
    int rr = tid >> 7, pos = (tid & 127) * 4;
    int row = rg * 2 + rr;
    const float* src = (is_gh ? slots : upd) + row * 512;
    f32x4 v = *(const f32x4*)&src[pos];
    if (!is_gh) v *= 1.f / (rowsum[row] + EPS_);
    *(f32x4*)&in_s[rr][pos] = v;
  }
  __syncthreads();
  int c0 = ccl * 256 + lane * 4;
  const float* __restrict__ W = is_gh ? whhT : wihT;
  f32x4 acc0 = {0.f, 0.f, 0.f, 0.f}, acc1 = acc0;
  for (int d = w * 128; d < w * 128 + 128; ++d) {
    f32x4 w4 = *(const f32x4*)&W[d * 1536 + c0];
    acc0 += in_s[0][d] * w4;
    acc1 += in_s[1][d] * w4;
  }
  *(f32x4*)&part[w][0][lane * 4] = acc0;
  *(f32x4*)&part[w][1][lane * 4] = acc1;
  __syncthreads();
  if (tid < 128) {
    int r = tid >> 6, ll = tid & 63;
    int cf = ccl * 256 + ll * 4;
    f32x4 s = *(const f32x4*)&part[0][r][ll * 4];
    s += *(const f32x4*)&part[1][r][ll * 4];
    s += *(const f32x4*)&part[2][r][ll * 4];
    s += *(const f32x4*)&part[3][r][ll * 4];
    s += *(const f32x4*)&(is_gh ? bhh : bih)[cf];
    *(f32x4*)&(is_gh ? gh : gx)[(rg * 2 + r) * 1536 + cf] = s;
  }
}

// ---------------- GRU elementwise + LN -> hnew, hln ----------------
__global__ __launch_bounds__(512) void gru_ln_kernel(
    const float* __restrict__ gx, const float* __restrict__ gh,
    const float* __restrict__ slots,
    const float* __restrict__ lnf_g, const float* __restrict__ lnf_b,
    float* __restrict__ hnew, float* __restrict__ hln)
{
  __shared__ float red1[8], red2[8];
  int tid = threadIdx.x, row = blockIdx.x;
  float gxr = gx[row * 1536 + tid], gxz = gx[row * 1536 + 512 + tid], gxn = gx[row * 1536 + 1024 + tid];
  float ghr = gh[row * 1536 + tid], ghz = gh[row * 1536 + 512 + tid], ghn = gh[row * 1536 + 1024 + tid];
  float h = slots[row * 512 + tid];
  float r_ = 1.f / (1.f + __expf(-(gxr + ghr)));
  float z_ = 1.f / (1.f + __expf(-(gxz + ghz)));
  float n_ = tanhf(gxn + r_ * ghn);
  float hn = (1.f - z_) * n_ + z_ * h;
  hnew[row * 512 + tid] = hn;
  float s1 = wave_red_sum(hn), s2 = wave_red_sum(hn * hn);
  int w = tid >> 6, lane = tid & 63;
  if (lane == 0) { red1[w] = s1; red2[w] = s2; }
  __syncthreads();
  s1 = 0.f; s2 = 0.f;
#pragma unroll
  for (int i = 0; i < 8; ++i) { s1 += red1[i]; s2 += red2[i]; }
  float mean = s1 * (1.f / 512.f);
  float var = s2 * (1.f / 512.f) - mean * mean;
  float rstd = rsqrtf(var + LN_EPS);
  hln[row * 512 + tid] = (hn - mean) * rstd * lnf_g[tid] + lnf_b[tid];
}

// ---------------- mlp1: act = relu(hln @ W1 + b1) ----------------
__global__ __launch_bounds__(256) void mlp1_kernel(
    const float* __restrict__ hln, const float* __restrict__ W1,
    const float* __restrict__ b1, float* __restrict__ act)
{
  __shared__ float in_s[2][512];
  __shared__ float part[4][2][64];
  int tid = threadIdx.x, w = tid >> 6, lane = tid & 63;
  int rg = blockIdx.x >> 3, cc = blockIdx.x & 7;
  {
    int rr = tid >> 7, pos = (tid & 127) * 4;
    *(f32x4*)&in_s[rr][pos] = *(const f32x4*)&hln[(rg * 2 + rr) * 512 + pos];
  }
  __syncthreads();
  int c = cc * 64 + lane;
  float a0 = 0.f, a1 = 0.f;
  for (int d = w * 128; d < w * 128 + 128; ++d) {
    float wv = W1[d * 512 + c];
    a0 += in_s[0][d] * wv;
    a1 += in_s[1][d] * wv;
  }
  part[w][0][lane] = a0;
  part[w][1][lane] = a1;
  __syncthreads();
  if (tid < 128) {
    int r = tid >> 6, ll = tid & 63;
    float s = part[0][r][ll] + part[1][r][ll] + part[2][r][ll] + part[3][r][ll]
            + b1[cc * 64 + ll];
    act[(rg * 2 + r) * 512 + cc * 64 + ll] = fmaxf(s, 0.f);
  }
}

// ---------------- mlp2: slots = hnew + act @ W2 + b2 ----------------
__global__ __launch_bounds__(256) void mlp2_kernel(
    const float* __restrict__ act, const float* __restrict__ W2,
    const float* __restrict__ b2, const float* __restrict__ hnew,
    float* __restrict__ slots)
{
  __shared__ float in_s[2][512];
  __shared__ float part[4][2][64];
  int tid = threadIdx.x, w = tid >> 6, lane = tid & 63;
  int rg = blockIdx.x >> 3, cc = blockIdx.x & 7;
  {
    int rr = tid >> 7, pos = (tid & 127) * 4;
    *(f32x4*)&in_s[rr][pos] = *(const f32x4*)&act[(rg * 2 + rr) * 512 + pos];
  }
  __syncthreads();
  int c = cc * 64 + lane;
  float a0 = 0.f, a1 = 0.f;
  for (int d = w * 128; d < w * 128 + 128; ++d) {
    float wv = W2[d * 512 + c];
    a0 += in_s[0][d] * wv;
    a1 += in_s[1][d] * wv;
  }
  part[w][0][lane] = a0;
  part[w][1][lane] = a1;
  __syncthreads();
  if (tid < 128) {
    int r = tid >> 6, ll = tid & 63;
    int row = rg * 2 + r, c2 = cc * 64 + ll;
    float s = part[0][r][ll] + part[1][r][ll] + part[2][r][ll] + part[3][r][ll] + b2[c2];
    slots[row * 512 + c2] = hnew[row * 512 + c2] + s;
  }
}

// ---------------- attn normalize in place ----------------
__global__ __launch_bounds__(256) void norm_attn(
    const float* __restrict__ rowsum, float* __restrict__ attn)
{
  int idx = blockIdx.x * 256 + threadIdx.x;  // < 131072
  int row = idx >> 11;
  attn[idx] = attn[idx] / (rowsum[row] + EPS_);
}

extern "C" void kernel_launch(void* const* d_in, const int* in_sizes, int n_in,
                              void* d_out, int out_size, void* d_ws, size_t ws_size,
                              hipStream_t stream)
{
  const float* inputs     = (const float*)d_in[0];
  const float* slots_init = (const float*)d_in[1];
  const float* Wq   = (const float*)d_in[2];
  const float* bq   = (const float*)d_in[3];
  const float* Wk   = (const float*)d_in[4];
  const float* bk   = (const float*)d_in[5];
  const float* Wv   = (const float*)d_in[6];
  const float* bv   = (const float*)d_in[7];
  const float* ln_in_g = (const float*)d_in[8];
  const float* ln_in_b = (const float*)d_in[9];
  const float* ln_s_g  = (const float*)d_in[10];
  const float* ln_s_b  = (const float*)d_in[11];
  const float* ln_f_g  = (const float*)d_in[12];
  const float* ln_f_b  = (const float*)d_in[13];
  const float* wih  = (const float*)d_in[14];
  const float* whh  = (const float*)d_in[15];
  const float* bih  = (const float*)d_in[16];
  const float* bhh  = (const float*)d_in[17];
  const float* W1   = (const float*)d_in[18];
  const float* b1   = (const float*)d_in[19];
  const float* W2   = (const float*)d_in[20];
  const float* b2   = (const float*)d_in[21];

  float* out   = (float*)d_out;
  float* slots = out;                 // [32,2,512] working + final output
  float* q_out = out + 32768;         // [32,2,512]
  float* k_out = out + 65536;         // [32,2048,512] fp32 k (required output)
  float* attnp = out + 33619968;      // [32,2,2048] attn (normalized at end)

  char* ws = (char*)d_ws;
  bf16_t* xbf   = (bf16_t*)(ws);                    // 67,108,864 LN(inputs) bf16 (dead after gemm)
  float*  upd_part = (float*)(ws);                  // 16,777,216 (alias xbf; live in iters)
  float*  rs_part  = (float*)(ws + 16777216);       //      8,192 (alias xbf)
  bf16_t* vbf   = (bf16_t*)(ws + 67108864);         // 67,108,864
  bf16_t* BT    = (bf16_t*)(ws + 134217728);        //  1,048,576 (dead after gemm)
  float*  gx    = (float*)(ws + 134217728);         //    393,216 (alias)
  float*  gh    = (float*)(ws + 134610944);         //    393,216
  float*  hnew  = (float*)(ws + 135004160);         //    131,072
  float*  hln   = (float*)(ws + 135135232);         //    131,072
  float*  wihT  = (float*)(ws + 135266304);         //  3,145,728
  float*  whhT  = (float*)(ws + 138412032);         //  3,145,728
  float*  biasc = (float*)(ws + 141557760);         //      4,096
  float*  act   = (float*)(ws + 141561856);         //    131,072
  float*  upd   = (float*)(ws + 142086144);         //    131,072
  float*  rowsum= (float*)(ws + 142217216);         //        256  -> end 142,217,472

  // optional bf16 k for attend, gated on workspace size
  const size_t kbf_off = 142217472ull;               // 16B aligned
  const bool big_ws = ws_size >= kbf_off + 67108864ull;
  bf16_t* kbf = big_ws ? (bf16_t*)(ws + kbf_off) : (bf16_t*)nullptr;

  transpose_prep<<<dim3(16, 48, 4), 256, 0, stream>>>(Wk, Wv, wih, whh, BT, wihT, whhT);
  small_prep<<<132, 256, 0, stream>>>(bk, bv, slots_init, biasc, slots);
  ln_apply<<<16384, 256, 0, stream>>>(inputs, ln_in_g, ln_in_b, xbf);
  gemm_kv<<<4096, 256, 0, stream>>>(xbf, BT, biasc, k_out, vbf, kbf);
  for (int it = 0; it < 3; ++it) {
    ln_q_kernel<<<256, 256, 0, stream>>>(slots, ln_s_g, ln_s_b, Wq, bq, q_out);
    if (big_ws)
      attend_bf16<<<1024, 256, 0, stream>>>(kbf, vbf, q_out, upd_part, rs_part, attnp);
    else
      attend_fused<<<1024, 256, 0, stream>>>(k_out, vbf, q_out, upd_part, rs_part, attnp);
    reduce_upd<<<64, 512, 0, stream>>>(upd_part, rs_part, upd, rowsum);
    gates_kernel<<<384, 256, 0, stream>>>(slots, upd, rowsum, wihT, whhT, bih, bhh, gx, gh);
    gru_ln_kernel<<<64, 512, 0, stream>>>(gx, gh, slots, ln_f_g, ln_f_b, hnew, hln);
    mlp1_kernel<<<256, 256, 0, stream>>>(hln, W1, b1, act);
    mlp2_kernel<<<256, 256, 0, stream>>>(act, W2, b2, hnew, slots);
  }
  norm_attn<<<512, 256, 0, stream>>>(rowsum, attnp);
}

// Round 8
// 598.329 us; speedup vs baseline: 1.6298x; 1.0322x over previous
//
#include <hip/hip_runtime.h>
#include <stdint.h>

typedef __bf16 bf16_t;
typedef bf16_t bf16x8 __attribute__((ext_vector_type(8)));
typedef float f32x4 __attribute__((ext_vector_type(4)));

typedef unsigned int u32;
typedef __attribute__((address_space(1))) const u32 gu32;
typedef __attribute__((address_space(3))) u32 lu32;

#define LN_EPS 1e-5f
#define EPS_ 1e-8f
#define SCALE_ 0.04419417382415922f  // 512^-0.5

__device__ __forceinline__ float wave_red_sum(float v) {
#pragma unroll
  for (int off = 32; off > 0; off >>= 1) v += __shfl_xor(v, off, 64);
  return v;
}

// ---------------- prep: LDS-tiled transposes (coalesced both sides) ----------------
__global__ __launch_bounds__(256) void transpose_prep(
    const float* __restrict__ Wk, const float* __restrict__ Wv,
    const float* __restrict__ wih, const float* __restrict__ whh,
    bf16_t* __restrict__ BT, float* __restrict__ wihT, float* __restrict__ whhT)
{
  int z = blockIdx.z;
  if (z < 2 && blockIdx.y >= 16) return;
  const float* src = (z == 0) ? Wk : (z == 1) ? Wv : (z == 2) ? wih : whh;
  __shared__ float tile[32][33];
  int tx = threadIdx.x & 31, ty = threadIdx.x >> 5;  // 32 x 8
  int row0 = blockIdx.y * 32, col0 = blockIdx.x * 32;
#pragma unroll
  for (int i = 0; i < 4; ++i)
    tile[ty + 8 * i][tx] = src[(size_t)(row0 + ty + 8 * i) * 512 + col0 + tx];
  __syncthreads();
  if (z < 2) {
#pragma unroll
    for (int i = 0; i < 4; ++i)
      BT[(size_t)(z * 512 + col0 + ty + 8 * i) * 512 + row0 + tx] =
          (bf16_t)tile[tx][ty + 8 * i];
  } else {
    float* dst = (z == 2) ? wihT : whhT;
#pragma unroll
    for (int i = 0; i < 4; ++i)
      dst[(size_t)(col0 + ty + 8 * i) * 1536 + row0 + tx] = tile[tx][ty + 8 * i];
  }
}

// ---------------- small prep: biasc pack + slots init (into d_out) ----------------
__global__ __launch_bounds__(256) void small_prep(
    const float* __restrict__ bk, const float* __restrict__ bv,
    const float* __restrict__ slots_init,
    float* __restrict__ biasc, float* __restrict__ slots)
{
  int idx = blockIdx.x * 256 + threadIdx.x;  // < 33792
  if (idx < 1024) {
    biasc[idx] = (idx < 512) ? bk[idx] : bv[idx - 512];
  } else {
    int i = idx - 1024;  // < 32768
    slots[i] = slots_init[i];
  }
}

// ---------------- LN(inputs) -> bf16, one wave per row ----------------
__global__ __launch_bounds__(256) void ln_apply(
    const float* __restrict__ in, const float* __restrict__ lng,
    const float* __restrict__ lnb, bf16_t* __restrict__ xbf)
{
  int w = threadIdx.x >> 6, lane = threadIdx.x & 63;
  size_t row = (size_t)blockIdx.x * 4 + w;
  const float4* rp = (const float4*)(in + row * 512);
  float4 a = rp[lane * 2], c = rp[lane * 2 + 1];
  float s1 = a.x + a.y + a.z + a.w + c.x + c.y + c.z + c.w;
  float s2 = a.x * a.x + a.y * a.y + a.z * a.z + a.w * a.w +
             c.x * c.x + c.y * c.y + c.z * c.z + c.w * c.w;
  s1 = wave_red_sum(s1);
  s2 = wave_red_sum(s2);
  float mean = s1 * (1.f / 512.f);
  float var = s2 * (1.f / 512.f) - mean * mean;
  float rs = rsqrtf(var + LN_EPS);
  float4 g0 = *(const float4*)&lng[lane * 8];
  float4 g1 = *(const float4*)&lng[lane * 8 + 4];
  float4 b0 = *(const float4*)&lnb[lane * 8];
  float4 b1 = *(const float4*)&lnb[lane * 8 + 4];
  bf16x8 o;
  o[0] = (bf16_t)((a.x - mean) * rs * g0.x + b0.x);
  o[1] = (bf16_t)((a.y - mean) * rs * g0.y + b0.y);
  o[2] = (bf16_t)((a.z - mean) * rs * g0.z + b0.z);
  o[3] = (bf16_t)((a.w - mean) * rs * g0.w + b0.w);
  o[4] = (bf16_t)((c.x - mean) * rs * g1.x + b1.x);
  o[5] = (bf16_t)((c.y - mean) * rs * g1.y + b1.y);
  o[6] = (bf16_t)((c.z - mean) * rs * g1.z + b1.z);
  o[7] = (bf16_t)((c.w - mean) * rs * g1.w + b1.w);
  *(bf16x8*)&xbf[row * 512 + lane * 8] = o;
}

// ---------------- bf16 MFMA GEMM: 2-phase pipelined dbuf + direct-register epilogue ----------------
__global__ __launch_bounds__(256) void gemm_kv(
    const bf16_t* __restrict__ xbf, const bf16_t* __restrict__ BT,
    const float* __restrict__ biasc,
    float* __restrict__ out_k, bf16_t* __restrict__ vbf, bf16_t* kbf)
{
  __shared__ __align__(16) char smem[32768];

  const int tid = threadIdx.x, lane = tid & 63, w = tid >> 6;
  const int quad = lane >> 4, l16 = lane & 15;
  const int l = blockIdx.x;
  const int x = l & 7, t0 = l >> 3;
  const int n0 = (t0 & 7) * 128;
  const int m0 = ((t0 >> 3) * 8 + x) * 128;
  const int mb = (w & 1) * 64, nb = (w >> 1) * 64;
  const int swz = (l16 >> 1) & 3;

  const bf16_t* a_base = xbf + (size_t)m0 * 512;
  const bf16_t* b_base = BT + (size_t)n0 * 512;

  f32x4 acc[4][4] = {};

  auto stage = [&](int buf, int kk) {
    bf16_t* As = (bf16_t*)(smem + buf * 16384);
    bf16_t* Bs = (bf16_t*)(smem + buf * 16384 + 8192);
#pragma unroll
    for (int r = 0; r < 2; ++r) {
      int tt = tid + r * 256;            // 0..511
      int rr = tt >> 2, pg = tt & 3;
      int lg = pg ^ ((rr >> 1) & 3);     // pre-swizzled source granule
      __builtin_amdgcn_global_load_lds((gu32*)(a_base + (size_t)rr * 512 + kk + lg * 8),
                                       (lu32*)&As[tt * 8], 16, 0, 0);
      __builtin_amdgcn_global_load_lds((gu32*)(b_base + (size_t)rr * 512 + kk + lg * 8),
                                       (lu32*)&Bs[tt * 8], 16, 0, 0);
    }
  };

  auto compute = [&](int buf) {
    const bf16_t* As = (const bf16_t*)(smem + buf * 16384);
    const bf16_t* Bs = (const bf16_t*)(smem + buf * 16384 + 8192);
    bf16x8 af[4], bfr[4];
#pragma unroll
    for (int mt = 0; mt < 4; ++mt)
      af[mt] = *(const bf16x8*)&As[(mb + mt * 16 + l16) * 32 + ((quad ^ swz) * 8)];
#pragma unroll
    for (int nt = 0; nt < 4; ++nt)
      bfr[nt] = *(const bf16x8*)&Bs[(nb + nt * 16 + l16) * 32 + ((quad ^ swz) * 8)];
#pragma unroll
    for (int mt = 0; mt < 4; ++mt)
#pragma unroll
      for (int nt = 0; nt < 4; ++nt)
        acc[mt][nt] = __builtin_amdgcn_mfma_f32_16x16x32_bf16(af[mt], bfr[nt], acc[mt][nt], 0, 0, 0);
  };

  stage(0, 0);
  __syncthreads();
#pragma unroll
  for (int t = 0; t < 16; ++t) {
    if (t < 15) stage((t + 1) & 1, (t + 1) * 32);
    compute(t & 1);
    if (t < 15) __syncthreads();
  }

  // ---- direct-register epilogue (no LDS, no barriers) ----
  const int is_k = (n0 < 512);
  const int rbase = m0 + mb + quad * 4;
  if (is_k) {
#pragma unroll
    for (int nt = 0; nt < 4; ++nt) {
      int col = n0 + nb + nt * 16 + l16;
      float bias = biasc[col];
#pragma unroll
      for (int mt = 0; mt < 4; ++mt) {
        int row = rbase + mt * 16;
#pragma unroll
        for (int r = 0; r < 4; ++r) {
          float v = acc[mt][nt][r] + bias;
          out_k[(size_t)(row + r) * 512 + col] = v;
        }
      }
    }
    if (kbf) {
#pragma unroll
      for (int nt = 0; nt < 4; ++nt) {
        int col = n0 + nb + nt * 16 + l16;
        float bias = biasc[col];
#pragma unroll
        for (int mt = 0; mt < 4; ++mt) {
          int row = rbase + mt * 16;
#pragma unroll
          for (int r = 0; r < 4; ++r)
            kbf[(size_t)(row + r) * 512 + col] = (bf16_t)(acc[mt][nt][r] + bias);
        }
      }
    }
  } else {
#pragma unroll
    for (int nt = 0; nt < 4; ++nt) {
      int colg = n0 + nb + nt * 16 + l16;
      float bias = biasc[colg];
      int col = colg - 512;
#pragma unroll
      for (int mt = 0; mt < 4; ++mt) {
        int row = rbase + mt * 16;
#pragma unroll
        for (int r = 0; r < 4; ++r)
          vbf[(size_t)(row + r) * 512 + col] = (bf16_t)(acc[mt][nt][r] + bias);
      }
    }
  }
}

// ---------------- ln_q v2: LN(slots) + q GEMV, mlp1-style split ----------------
__global__ __launch_bounds__(256) void ln_q_kernel(
    const float* __restrict__ slots,
    const float* __restrict__ lnsg, const float* __restrict__ lnsb,
    const float* __restrict__ Wq, const float* __restrict__ bq,
    float* __restrict__ q_out)
{
  __shared__ float s[2][512];
  __shared__ float part[4][2][64];
  __shared__ float red1[4], red2[4];
  int tid = threadIdx.x, w = tid >> 6, lane = tid & 63;
  int b = blockIdx.x >> 3, cg = blockIdx.x & 7;

  int r = tid >> 7;
  int off = (tid * 4) & 511;
  float4 v = *(const float4*)&slots[b * 1024 + tid * 4];
  float s1 = v.x + v.y + v.z + v.w;
  float s2 = v.x * v.x + v.y * v.y + v.z * v.z + v.w * v.w;
  s1 = wave_red_sum(s1);
  s2 = wave_red_sum(s2);
  if (lane == 0) { red1[w] = s1; red2[w] = s2; }
  __syncthreads();
  float mean = (red1[r * 2] + red1[r * 2 + 1]) * (1.f / 512.f);
  float var = (red2[r * 2] + red2[r * 2 + 1]) * (1.f / 512.f) - mean * mean;
  float rstd = rsqrtf(var + LN_EPS);
  float4 g4 = *(const float4*)&lnsg[off];
  float4 b4 = *(const float4*)&lnsb[off];
  s[r][off + 0] = (v.x - mean) * rstd * g4.x + b4.x;
  s[r][off + 1] = (v.y - mean) * rstd * g4.y + b4.y;
  s[r][off + 2] = (v.z - mean) * rstd * g4.z + b4.z;
  s[r][off + 3] = (v.w - mean) * rstd * g4.w + b4.w;
  __syncthreads();

  int c = cg * 64 + lane;
  float a0 = 0.f, a1 = 0.f;
  for (int d = w * 128; d < w * 128 + 128; ++d) {
    float wv = Wq[d * 512 + c];
    a0 += s[0][d] * wv;
    a1 += s[1][d] * wv;
  }
  part[w][0][lane] = a0;
  part[w][1][lane] = a1;
  __syncthreads();
  if (tid < 128) {
    int rr = tid >> 6, ll = tid & 63;
    float sum = part[0][rr][ll] + part[1][rr][ll] + part[2][rr][ll] + part[3][rr][ll]
              + bq[cg * 64 + ll];
    q_out[(b * 2 + rr) * 512 + cg * 64 + ll] = sum;
  }
}

// ---------------- attend v3 (fp32 k fallback): unchanged ----------------
__global__ __launch_bounds__(256) void attend_fused(
    const float* __restrict__ kf, const bf16_t* __restrict__ vbf,
    const float* __restrict__ qf,
    float* __restrict__ upd_part, float* __restrict__ rs_part,
    float* __restrict__ attn_pre)
{
  __shared__ float qs[2][528];
  __shared__ float p_s[2][64];
  int tid = threadIdx.x, w = tid >> 6, lane = tid & 63;
  int b = blockIdx.x >> 5, chunk = blockIdx.x & 31;
  int j0 = chunk * 64;

  {
    int slot = tid >> 7, pos = (tid & 127) * 4;
    int dq = pos >> 7, dd = pos & 127;
    *(f32x4*)&qs[slot][dq * 132 + dd] = *(const f32x4*)&qf[b * 1024 + slot * 512 + pos];
  }
  __syncthreads();

  int jj = lane & 15;
  int dq = lane >> 4;
  const float* kp = kf + (size_t)(b * 2048 + j0 + w * 16 + jj) * 512 + dq * 128;
  const float* qb0 = &qs[0][dq * 132];
  const float* qb1 = &qs[1][dq * 132];
  float dot0 = 0.f, dot1 = 0.f;
#pragma unroll
  for (int h = 0; h < 4; ++h) {
    f32x4 kr[8];
#pragma unroll
    for (int i = 0; i < 8; ++i) kr[i] = *(const f32x4*)(kp + h * 32 + i * 4);
#pragma unroll
    for (int i = 0; i < 8; ++i) {
      f32x4 qa = *(const f32x4*)(qb0 + h * 32 + i * 4);
      f32x4 qc = *(const f32x4*)(qb1 + h * 32 + i * 4);
#pragma unroll
      for (int t = 0; t < 4; ++t) {
        dot0 += kr[i][t] * qa[t];
        dot1 += kr[i][t] * qc[t];
      }
    }
  }
  dot0 += __shfl_xor(dot0, 16, 64);
  dot0 += __shfl_xor(dot0, 32, 64);
  dot1 += __shfl_xor(dot1, 16, 64);
  dot1 += __shfl_xor(dot1, 32, 64);
  float d0f = dot0 * SCALE_, d1f = dot1 * SCALE_;
  float mx = fmaxf(d0f, d1f);
  float e0 = __expf(d0f - mx), e1 = __expf(d1f - mx);
  float inv = 1.f / (e0 + e1);
  float p0 = e0 * inv, p1 = e1 * inv;
  if (lane < 16) {
    int jj2 = w * 16 + lane;
    p_s[0][jj2] = p0;
    p_s[1][jj2] = p1;
    attn_pre[(b * 2 + 0) * 2048 + j0 + jj2] = p0;
    attn_pre[(b * 2 + 1) * 2048 + j0 + jj2] = p1;
  }
  __syncthreads();

  if (w == 0) {
    float a = p_s[0][lane];
    float c = p_s[1][lane];
    a = wave_red_sum(a);
    c = wave_red_sum(c);
    if (lane == 0) {
      rs_part[(b * 2 + 0) * 32 + chunk] = a;
      rs_part[(b * 2 + 1) * 32 + chunk] = c;
    }
  }

  float u0[8] = {}, u1[8] = {};
  const bf16_t* vp = vbf + (size_t)(b * 2048 + j0 + w * 16) * 512 + lane * 8;
  for (int t = 0; t < 16; ++t) {
    float p0b = p_s[0][w * 16 + t];
    float p1b = p_s[1][w * 16 + t];
    bf16x8 vv = *(const bf16x8*)(vp + (size_t)t * 512);
#pragma unroll
    for (int tt = 0; tt < 8; ++tt) {
      float vfl = (float)vv[tt];
      u0[tt] += p0b * vfl;
      u1[tt] += p1b * vfl;
    }
  }
  float* up0 = upd_part + ((size_t)(chunk * 4 + w) * 64 + b * 2 + 0) * 512 + lane * 8;
  f32x4 w0a = {u0[0], u0[1], u0[2], u0[3]}, w0b = {u0[4], u0[5], u0[6], u0[7]};
  f32x4 w1a = {u1[0], u1[1], u1[2], u1[3]}, w1b = {u1[4], u1[5], u1[6], u1[7]};
  *(f32x4*)(up0) = w0a;
  *(f32x4*)(up0 + 4) = w0b;
  *(f32x4*)(up0 + 512) = w1a;
  *(f32x4*)(up0 + 516) = w1b;
}

// ---------------- attend v4 (bf16 k): coalesced row loads + LDS transpose reduce ----------------
// Phase 1: per wave, j's loaded SEQUENTIALLY; lane covers the full 512-col row (64x8 bf16)
// -> 1KB fully-coalesced bursts over a contiguous 16KB region (streaming-friendly).
// Per-lane partials -> red[slot][j][lane]; 2-lane teams reduce; slot softmax via shfl_xor(32).
__global__ __launch_bounds__(256) void attend_bf16(
    const bf16_t* __restrict__ kbf, const bf16_t* __restrict__ vbf,
    const float* __restrict__ qf,
    float* __restrict__ upd_part, float* __restrict__ rs_part,
    float* __restrict__ attn_pre)
{
  __shared__ float red[2][64][68];   // 34,816 B; [slot][block j][lane], +4 pad
  __shared__ float p_s[2][64];
  int tid = threadIdx.x, w = tid >> 6, lane = tid & 63;
  int b = blockIdx.x >> 5, chunk = blockIdx.x & 31;
  int j0 = chunk * 64;

  // q in registers: lane owns cols lane*8..+8 of both slots
  const float* qb = qf + b * 1024;
  f32x4 q0a = *(const f32x4*)(qb + lane * 8);
  f32x4 q0b = *(const f32x4*)(qb + lane * 8 + 4);
  f32x4 q1a = *(const f32x4*)(qb + 512 + lane * 8);
  f32x4 q1b = *(const f32x4*)(qb + 512 + lane * 8 + 4);

  // ---- phase 1: coalesced k row loads, per-lane partial dots ----
  const bf16_t* kp = kbf + (size_t)(b * 2048 + j0 + w * 16) * 512 + lane * 8;
#pragma unroll
  for (int j = 0; j < 16; ++j) {
    bf16x8 kk = *(const bf16x8*)(kp + (size_t)j * 512);
    float d0 = 0.f, d1 = 0.f;
#pragma unroll
    for (int t = 0; t < 4; ++t) {
      float klo = (float)kk[t], khi = (float)kk[t + 4];
      d0 += klo * q0a[t] + khi * q0b[t];
      d1 += klo * q1a[t] + khi * q1b[t];
    }
    red[0][w * 16 + j][lane] = d0;
    red[1][w * 16 + j][lane] = d1;
  }
  __syncthreads();

  // ---- transpose reduce: 2 lanes per (slot, j) pair ----
  int pr = lane >> 1, half = lane & 1;
  int slot = pr >> 4, jl = pr & 15;
  const float* rr = &red[slot][w * 16 + jl][half * 32];
  f32x4 s4 = {0.f, 0.f, 0.f, 0.f};
#pragma unroll
  for (int k = 0; k < 8; ++k) s4 += *(const f32x4*)(rr + k * 4);
  float s = s4[0] + s4[1] + s4[2] + s4[3];
  s += __shfl_xor(s, 1, 64);
  float d = s * SCALE_;
  float dother = __shfl_xor(d, 32, 64);   // other slot, same j
  float mx = fmaxf(d, dother);
  float e = __expf(d - mx), eo = __expf(dother - mx);
  float inv = 1.f / (e + eo);
  float p = e * inv;
  if (half == 0) {
    p_s[slot][w * 16 + jl] = p;
    attn_pre[(b * 2 + slot) * 2048 + j0 + w * 16 + jl] = p;
  }
  __syncthreads();

  // rowsum partials: wave 0 reduces the block's 64 p's per slot
  if (w == 0) {
    float a = p_s[0][lane];
    float c = p_s[1][lane];
    a = wave_red_sum(a);
    c = wave_red_sum(c);
    if (lane == 0) {
      rs_part[(b * 2 + 0) * 32 + chunk] = a;
      rs_part[(b * 2 + 1) * 32 + chunk] = c;
    }
  }

  // ---- phase 2: weighted-v accumulate (coalesced) ----
  float u0[8] = {}, u1[8] = {};
  const bf16_t* vp = vbf + (size_t)(b * 2048 + j0 + w * 16) * 512 + lane * 8;
  for (int t = 0; t < 16; ++t) {
    float p0b = p_s[0][w * 16 + t];
    float p1b = p_s[1][w * 16 + t];
    bf16x8 vv = *(const bf16x8*)(vp + (size_t)t * 512);
#pragma unroll
    for (int tt = 0; tt < 8; ++tt) {
      float vfl = (float)vv[tt];
      u0[tt] += p0b * vfl;
      u1[tt] += p1b * vfl;
    }
  }
  float* up0 = upd_part + ((size_t)(chunk * 4 + w) * 64 + b * 2 + 0) * 512 + lane * 8;
  f32x4 w0a = {u0[0], u0[1], u0[2], u0[3]}, w0b = {u0[4], u0[5], u0[6], u0[7]};
  f32x4 w1a = {u1[0], u1[1], u1[2], u1[3]}, w1b = {u1[4], u1[5], u1[6], u1[7]};
  *(f32x4*)(up0) = w0a;
  *(f32x4*)(up0 + 4) = w0b;
  *(f32x4*)(up0 + 512) = w1a;
  *(f32x4*)(up0 + 516) = w1b;
}

// ---------------- reduce_upd: sum 128 partials -> upd, rowsum ----------------
__global__ __launch_bounds__(512) void reduce_upd(
    const float* __restrict__ upd_part, const float* __restrict__ rs_part,
    float* __restrict__ upd, float* __restrict__ rowsum)
{
  int r = blockIdx.x, tid = threadIdx.x;
  const float* p = upd_part + (size_t)r * 512 + tid;
  float acc = 0.f;
#pragma unroll 8
  for (int i = 0; i < 128; ++i) acc += p[(size_t)i * 32768];
  upd[r * 512 + tid] = acc;
  if (tid < 64) {
    float v = (tid < 32) ? rs_part[r * 32 + tid] : 0.f;
    v = wave_red_sum(v);
    if (tid == 0) rowsum[r] = v;
  }
}

// ---------------- gates: gx = u@wihT + bih, gh = h@whhT + bhh ----------------
__global__ __launch_bounds__(256) void gates_kernel(
    const float* __restrict__ slots, const float* __restrict__ upd,
    const float* __restrict__ rowsum,
    const float* __restrict__ wihT, const float* __restrict__ whhT,
    const float* __restrict__ bih, const float* __restrict__ bhh,
    float* __restrict__ gx, float* __restrict__ gh)
{
  __shared__ float in_s[2][512];
  __shared__ float part[4][2][256];
  int tid = threadIdx.x, w = tid >> 6, lane = tid & 63;
  int rg = blockIdx.x / 12, cc = blockIdx.x % 12;
  int is_gh = (cc >= 6);
  int ccl = is_gh ? cc - 6 : cc;
  {
    int rr = tid >> 7, pos = (tid & 127) * 4;
    int row = rg * 2 + rr;
    const float* src = (is_gh ? slots : upd) + row * 512;
    f32x4 v = *(const f32x4*)&src[pos];
    if (!is_gh) v *= 1.f / (rowsum[row] + EPS_);
    *(f32x4*)&in_s[rr][pos] = v;
  }
  __syncthreads();
  int c0 = ccl * 256 + lane * 4;
  const float* __restrict__ W = is_gh ? whhT : wihT;
  f32x4 acc0 = {0.f, 0.f, 0.f, 0.f}, acc1 = acc0;
  for (int d = w * 128; d < w * 128 + 128; ++d) {
    f32x4 w4 = *(const f32x4*)&W[d * 1536 + c0];
    acc0 += in_s[0][d] * w4;
    acc1 += in_s[1][d] * w4;
  }
  *(f32x4*)&part[w][0][lane * 4] = acc0;
  *(f32x4*)&part[w][1][lane * 4] = acc1;
  __syncthreads();
  if (tid < 128) {
    int r = tid >> 6, ll = tid & 63;
    int cf = ccl * 256 + ll * 4;
    f32x4 s = *(const f32x4*)&part[0][r][ll * 4];
    s += *(const f32x4*)&part[1][r][ll * 4];
    s += *(const f32x4*)&part[2][r][ll * 4];
    s += *(const f32x4*)&part[3][r][ll * 4];
    s += *(const f32x4*)&(is_gh ? bhh : bih)[cf];
    *(f32x4*)&(is_gh ? gh : gx)[(rg * 2 + r) * 1536 + cf] = s;
  }
}

// ---------------- GRU elementwise + LN -> hnew, hln ----------------
__global__ __launch_bounds__(512) void gru_ln_kernel(
    const float* __restrict__ gx, const float* __restrict__ gh,
    const float* __restrict__ slots,
    const float* __restrict__ lnf_g, const float* __restrict__ lnf_b,
    float* __restrict__ hnew, float* __restrict__ hln)
{
  __shared__ float red1[8], red2[8];
  int tid = threadIdx.x, row = blockIdx.x;
  float gxr = gx[row * 1536 + tid], gxz = gx[row * 1536 + 512 + tid], gxn = gx[row * 1536 + 1024 + tid];
  float ghr = gh[row * 1536 + tid], ghz = gh[row * 1536 + 512 + tid], ghn = gh[row * 1536 + 1024 + tid];
  float h = slots[row * 512 + tid];
  float r_ = 1.f / (1.f + __expf(-(gxr + ghr)));
  float z_ = 1.f / (1.f + __expf(-(gxz + ghz)));
  float n_ = tanhf(gxn + r_ * ghn);
  float hn = (1.f - z_) * n_ + z_ * h;
  hnew[row * 512 + tid] = hn;
  float s1 = wave_red_sum(hn), s2 = wave_red_sum(hn * hn);
  int w = tid >> 6, lane = tid & 63;
  if (lane == 0) { red1[w] = s1; red2[w] = s2; }
  __syncthreads();
  s1 = 0.f; s2 = 0.f;
#pragma unroll
  for (int i = 0; i < 8; ++i) { s1 += red1[i]; s2 += red2[i]; }
  float mean = s1 * (1.f / 512.f);
  float var = s2 * (1.f / 512.f) - mean * mean;
  float rstd = rsqrtf(var + LN_EPS);
  hln[row * 512 + tid] = (hn - mean) * rstd * lnf_g[tid] + lnf_b[tid];
}

// ---------------- mlp1: act = relu(hln @ W1 + b1) ----------------
__global__ __launch_bounds__(256) void mlp1_kernel(
    const float* __restrict__ hln, const float* __restrict__ W1,
    const float* __restrict__ b1, float* __restrict__ act)
{
  __shared__ float in_s[2][512];
  __shared__ float part[4][2][64];
  int tid = threadIdx.x, w = tid >> 6, lane = tid & 63;
  int rg = blockIdx.x >> 3, cc = blockIdx.x & 7;
  {
    int rr = tid >> 7, pos = (tid & 127) * 4;
    *(f32x4*)&in_s[rr][pos] = *(const f32x4*)&hln[(rg * 2 + rr) * 512 + pos];
  }
  __syncthreads();
  int c = cc * 64 + lane;
  float a0 = 0.f, a1 = 0.f;
  for (int d = w * 128; d < w * 128 + 128; ++d) {
    float wv = W1[d * 512 + c];
    a0 += in_s[0][d] * wv;
    a1 += in_s[1][d] * wv;
  }
  part[w][0][lane] = a0;
  part[w][1][lane] = a1;
  __syncthreads();
  if (tid < 128) {
    int r = tid >> 6, ll = tid & 63;
    float s = part[0][r][ll] + part[1][r][ll] + part[2][r][ll] + part[3][r][ll]
            + b1[cc * 64 + ll];
    act[(rg * 2 + r) * 512 + cc * 64 + ll] = fmaxf(s, 0.f);
  }
}

// ---------------- mlp2: slots = hnew + act @ W2 + b2 ----------------
__global__ __launch_bounds__(256) void mlp2_kernel(
    const float* __restrict__ act, const float* __restrict__ W2,
    const float* __restrict__ b2, const float* __restrict__ hnew,
    float* __restrict__ slots)
{
  __shared__ float in_s[2][512];
  __shared__ float part[4][2][64];
  int tid = threadIdx.x, w = tid >> 6, lane = tid & 63;
  int rg = blockIdx.x >> 3, cc = blockIdx.x & 7;
  {
    int rr = tid >> 7, pos = (tid & 127) * 4;
    *(f32x4*)&in_s[rr][pos] = *(const f32x4*)&act[(rg * 2 + rr) * 512 + pos];
  }
  __syncthreads();
  int c = cc * 64 + lane;
  float a0 = 0.f, a1 = 0.f;
  for (int d = w * 128; d < w * 128 + 128; ++d) {
    float wv = W2[d * 512 + c];
    a0 += in_s[0][d] * wv;
    a1 += in_s[1][d] * wv;
  }
  part[w][0][lane] = a0;
  part[w][1][lane] = a1;
  __syncthreads();
  if (tid < 128) {
    int r = tid >> 6, ll = tid & 63;
    int row = rg * 2 + r, c2 = cc * 64 + ll;
    float s = part[0][r][ll] + part[1][r][ll] + part[2][r][ll] + part[3][r][ll] + b2[c2];
    slots[row * 512 + c2] = hnew[row * 512 + c2] + s;
  }
}

// ---------------- attn normalize in place ----------------
__global__ __launch_bounds__(256) void norm_attn(
    const float* __restrict__ rowsum, float* __restrict__ attn)
{
  int idx = blockIdx.x * 256 + threadIdx.x;  // < 131072
  int row = idx >> 11;
  attn[idx] = attn[idx] / (rowsum[row] + EPS_);
}

extern "C" void kernel_launch(void* const* d_in, const int* in_sizes, int n_in,
                              void* d_out, int out_size, void* d_ws, size_t ws_size,
                              hipStream_t stream)
{
  const float* inputs     = (const float*)d_in[0];
  const float* slots_init = (const float*)d_in[1];
  const float* Wq   = (const float*)d_in[2];
  const float* bq   = (const float*)d_in[3];
  const float* Wk   = (const float*)d_in[4];
  const float* bk   = (const float*)d_in[5];
  const float* Wv   = (const float*)d_in[6];
  const float* bv   = (const float*)d_in[7];
  const float* ln_in_g = (const float*)d_in[8];
  const float* ln_in_b = (const float*)d_in[9];
  const float* ln_s_g  = (const float*)d_in[10];
  const float* ln_s_b  = (const float*)d_in[11];
  const float* ln_f_g  = (const float*)d_in[12];
  const float* ln_f_b  = (const float*)d_in[13];
  const float* wih  = (const float*)d_in[14];
  const float* whh  = (const float*)d_in[15];
  const float* bih  = (const float*)d_in[16];
  const float* bhh  = (const float*)d_in[17];
  const float* W1   = (const float*)d_in[18];
  const float* b1   = (const float*)d_in[19];
  const float* W2   = (const float*)d_in[20];
  const float* b2   = (const float*)d_in[21];

  float* out   = (float*)d_out;
  float* slots = out;                 // [32,2,512] working + final output
  float* q_out = out + 32768;         // [32,2,512]
  float* k_out = out + 65536;         // [32,2048,512] fp32 k (required output)
  float* attnp = out + 33619968;      // [32,2,2048] attn (normalized at end)

  char* ws = (char*)d_ws;
  bf16_t* xbf   = (bf16_t*)(ws);                    // 67,108,864 LN(inputs) bf16 (dead after gemm)
  float*  upd_part = (float*)(ws);                  // 16,777,216 (alias xbf; live in iters)
  float*  rs_part  = (float*)(ws + 16777216);       //      8,192 (alias xbf)
  bf16_t* vbf   = (bf16_t*)(ws + 67108864);         // 67,108,864
  bf16_t* BT    = (bf16_t*)(ws + 134217728);        //  1,048,576 (dead after gemm)
  float*  gx    = (float*)(ws + 134217728);         //    393,216 (alias)
  float*  gh    = (float*)(ws + 134610944);         //    393,216
  float*  hnew  = (float*)(ws + 135004160);         //    131,072
  float*  hln   = (float*)(ws + 135135232);         //    131,072
  float*  wihT  = (float*)(ws + 135266304);         //  3,145,728
  float*  whhT  = (float*)(ws + 138412032);         //  3,145,728
  float*  biasc = (float*)(ws + 141557760);         //      4,096
  float*  act   = (float*)(ws + 141561856);         //    131,072
  float*  upd   = (float*)(ws + 142086144);         //    131,072
  float*  rowsum= (float*)(ws + 142217216);         //        256  -> end 142,217,472

  // optional bf16 k for attend, gated on workspace size
  const size_t kbf_off = 142217472ull;               // 16B aligned
  const bool big_ws = ws_size >= kbf_off + 67108864ull;
  bf16_t* kbf = big_ws ? (bf16_t*)(ws + kbf_off) : (bf16_t*)nullptr;

  transpose_prep<<<dim3(16, 48, 4), 256, 0, stream>>>(Wk, Wv, wih, whh, BT, wihT, whhT);
  small_prep<<<132, 256, 0, stream>>>(bk, bv, slots_init, biasc, slots);
  ln_apply<<<16384, 256, 0, stream>>>(inputs, ln_in_g, ln_in_b, xbf);
  gemm_kv<<<4096, 256, 0, stream>>>(xbf, BT, biasc, k_out, vbf, kbf);
  for (int it = 0; it < 3; ++it) {
    ln_q_kernel<<<256, 256, 0, stream>>>(slots, ln_s_g, ln_s_b, Wq, bq, q_out);
    if (big_ws)
      attend_bf16<<<1024, 256, 0, stream>>>(kbf, vbf, q_out, upd_part, rs_part, attnp);
    else
      attend_fused<<<1024, 256, 0, stream>>>(k_out, vbf, q_out, upd_part, rs_part, attnp);
    reduce_upd<<<64, 512, 0, stream>>>(upd_part, rs_part, upd, rowsum);
    gates_kernel<<<384, 256, 0, stream>>>(slots, upd, rowsum, wihT, whhT, bih, bhh, gx, gh);
    gru_ln_kernel<<<64, 512, 0, stream>>>(gx, gh, slots, ln_f_g, ln_f_b, hnew, hln);
    mlp1_kernel<<<256, 256, 0, stream>>>(hln, W1, b1, act);
    mlp2_kernel<<<256, 256, 0, stream>>>(act, W2, b2, hnew, slots);
  }
  norm_attn<<<512, 256, 0, stream>>>(rowsum, attnp);
}